// Round 1
// baseline (2421.002 us; speedup 1.0000x reference)
//
#include <hip/hip_runtime.h>
#include <hip/hip_bf16.h>
#include <cmath>

// ---------------------------------------------------------------------------
// RWKV-7 TimeMixing, fp32 baseline.
// B=2, T=2048, C=1024, H=16, N=64. M = B*T = 4096.
// 12 NT-GEMMs (out = A @ W^T) with fused token-shift A-load and fused
// activation epilogues; WKV7 scan (serial T, parallel B*H*4); fused
// LN + rkv + gate kernel.
// ---------------------------------------------------------------------------

#define BM 64
#define BN 64
#define BK 32

enum { A_PLAIN = 0, A_MIX = 1 };
enum { EP_STORE = 0, EP_TANH = 1, EP_W = 2, EP_SIGMOID = 3, EP_AK = 4, EP_VBLEND = 5 };

__device__ __forceinline__ float sigf(float x) { return 1.f / (1.f + expf(-x)); }

// out[m,n] = sum_c A[m,c] * W[n,c]   (A: MxK, W: NxK, both row-major)
// AMODE==A_MIX: A[m,c] = x[m,c] + (x_prev[m,c]-x[m,c])*tm[c], x_prev = 0 at t==0
template<int AMODE, int EPI>
__global__ __launch_bounds__(256)
void gemm_nt(const float* __restrict__ A, const float* __restrict__ tm,
             const float* __restrict__ W, float* __restrict__ O,
             const float* __restrict__ bias, const float* __restrict__ extra,
             int M, int K, int N, int Tdim)
{
    __shared__ float As[BK][BM + 4];
    __shared__ float Bs[BK][BN + 4];
    const int tid  = threadIdx.x;
    const int m0   = blockIdx.y * BM;
    const int n0   = blockIdx.x * BN;
    const int lrow = tid >> 3;          // 0..31
    const int lcol = (tid & 7) << 2;    // 0..28 step 4
    const int ty   = tid >> 4;          // 0..15
    const int tx   = tid & 15;          // 0..15
    float acc[4][4] = {{0.f}};

    for (int k0 = 0; k0 < K; k0 += BK) {
#pragma unroll
        for (int rr = 0; rr < 2; ++rr) {
            const int row = lrow + rr * 32;
            const int m   = m0 + row;
            float4 av;
            if (AMODE == A_MIX) {
                const float4 xc = *(const float4*)&A[(size_t)m * K + k0 + lcol];
                float4 xp = make_float4(0.f, 0.f, 0.f, 0.f);
                if ((m % Tdim) != 0)
                    xp = *(const float4*)&A[(size_t)(m - 1) * K + k0 + lcol];
                const float4 tc = *(const float4*)&tm[k0 + lcol];
                av.x = xc.x + (xp.x - xc.x) * tc.x;
                av.y = xc.y + (xp.y - xc.y) * tc.y;
                av.z = xc.z + (xp.z - xc.z) * tc.z;
                av.w = xc.w + (xp.w - xc.w) * tc.w;
            } else {
                av = *(const float4*)&A[(size_t)m * K + k0 + lcol];
            }
            As[lcol + 0][row] = av.x; As[lcol + 1][row] = av.y;
            As[lcol + 2][row] = av.z; As[lcol + 3][row] = av.w;
            const float4 bv = *(const float4*)&W[(size_t)(n0 + row) * K + k0 + lcol];
            Bs[lcol + 0][row] = bv.x; Bs[lcol + 1][row] = bv.y;
            Bs[lcol + 2][row] = bv.z; Bs[lcol + 3][row] = bv.w;
        }
        __syncthreads();
#pragma unroll
        for (int kk = 0; kk < BK; ++kk) {
            const float4 a4 = *(const float4*)&As[kk][ty << 2];
            const float4 b4 = *(const float4*)&Bs[kk][tx << 2];
            acc[0][0] += a4.x * b4.x; acc[0][1] += a4.x * b4.y; acc[0][2] += a4.x * b4.z; acc[0][3] += a4.x * b4.w;
            acc[1][0] += a4.y * b4.x; acc[1][1] += a4.y * b4.y; acc[1][2] += a4.y * b4.z; acc[1][3] += a4.y * b4.w;
            acc[2][0] += a4.z * b4.x; acc[2][1] += a4.z * b4.y; acc[2][2] += a4.z * b4.z; acc[2][3] += a4.z * b4.w;
            acc[3][0] += a4.w * b4.x; acc[3][1] += a4.w * b4.y; acc[3][2] += a4.w * b4.z; acc[3][3] += a4.w * b4.w;
        }
        __syncthreads();
    }

#pragma unroll
    for (int ii = 0; ii < 4; ++ii) {
        const int m = m0 + (ty << 2) + ii;
        const int n = n0 + (tx << 2);
        const size_t o = (size_t)m * N + n;
        const float a0v = acc[ii][0], a1v = acc[ii][1], a2v = acc[ii][2], a3v = acc[ii][3];
        float4 res;
        if (EPI == EP_STORE) {
            res = make_float4(a0v, a1v, a2v, a3v);
        } else if (EPI == EP_TANH) {
            res = make_float4(tanhf(a0v), tanhf(a1v), tanhf(a2v), tanhf(a3v));
        } else if (EPI == EP_SIGMOID) {
            res = make_float4(sigf(a0v), sigf(a1v), sigf(a2v), sigf(a3v));
        } else if (EPI == EP_W) {
            const float4 b = *(const float4*)&bias[n];
            res.x = expf(-0.606531f * sigf(b.x + a0v));
            res.y = expf(-0.606531f * sigf(b.y + a1v));
            res.z = expf(-0.606531f * sigf(b.z + a2v));
            res.w = expf(-0.606531f * sigf(b.w + a3v));
        } else if (EPI == EP_AK) {
            const float4 b  = *(const float4*)&bias[n];
            const float4 ka = *(const float4*)&extra[n];
            const float4 kv = *(const float4*)&O[o];
            res.x = kv.x * (1.f + (sigf(b.x + a0v) - 1.f) * ka.x);
            res.y = kv.y * (1.f + (sigf(b.y + a1v) - 1.f) * ka.y);
            res.z = kv.z * (1.f + (sigf(b.z + a2v) - 1.f) * ka.z);
            res.w = kv.w * (1.f + (sigf(b.w + a3v) - 1.f) * ka.w);
        } else { // EP_VBLEND: O (=v) += (v_first - v) * sigmoid(bias + acc)
            const float4 b  = *(const float4*)&bias[n];
            const float4 vf = *(const float4*)&extra[o];
            const float4 vv = *(const float4*)&O[o];
            float s;
            s = sigf(b.x + a0v); res.x = vv.x + (vf.x - vv.x) * s;
            s = sigf(b.y + a1v); res.y = vv.y + (vf.y - vv.y) * s;
            s = sigf(b.z + a2v); res.z = vv.z + (vf.z - vv.z) * s;
            s = sigf(b.w + a3v); res.w = vv.w + (vf.w - vv.w) * s;
        }
        *(float4*)&O[o] = res;
    }
}

// WKV7 scan: state[i,j] = state[i,j]*w[i] + k[i]*v[j]; y[i] = sum_j state[i,j]*r[j]
// grid = B*H*4 blocks (4-way split of i), 64 lanes. lane = il*4+q:
// owns rows i = s*16+il, j-range [16q, 16q+16). 4 timesteps per barrier pair.
__global__ __launch_bounds__(64)
void wkv7_scan(const float* __restrict__ r, const float* __restrict__ w,
               const float* __restrict__ k, const float* __restrict__ v,
               float* __restrict__ y, int Bn, int Tn, int Hn)
{
    const int blk  = blockIdx.x;
    const int s    = blk & 3;
    const int h    = (blk >> 2) % Hn;
    const int b    = blk / (4 * Hn);
    const int lane = threadIdx.x;
    const int il   = lane >> 2;
    const int q    = lane & 3;
    const int i    = s * 16 + il;
    const int C    = Hn * 64;
    const size_t base = (size_t)b * Tn * C + h * 64;

    float st[16];
#pragma unroll
    for (int j = 0; j < 16; ++j) st[j] = 0.f;

    __shared__ float vs[4][64];
    __shared__ float rs[4][64];

    for (int t0 = 0; t0 < Tn; t0 += 4) {
        float vl[4], rl[4], wl[4], kl[4];
#pragma unroll
        for (int u = 0; u < 4; ++u) {
            const size_t off = base + (size_t)(t0 + u) * C;
            vl[u] = v[off + lane]; rl[u] = r[off + lane];
            wl[u] = w[off + i];    kl[u] = k[off + i];
        }
        __syncthreads();   // WAR: previous chunk's reads done before overwrite
#pragma unroll
        for (int u = 0; u < 4; ++u) { vs[u][lane] = vl[u]; rs[u][lane] = rl[u]; }
        __syncthreads();
#pragma unroll
        for (int u = 0; u < 4; ++u) {
            const float wi = wl[u], ki = kl[u];
            float yi = 0.f;
#pragma unroll
            for (int jg = 0; jg < 4; ++jg) {
                const float4 v4 = *(const float4*)&vs[u][q * 16 + jg * 4];
                const float4 r4 = *(const float4*)&rs[u][q * 16 + jg * 4];
                const int j = jg * 4;
                st[j + 0] = st[j + 0] * wi + ki * v4.x; yi += st[j + 0] * r4.x;
                st[j + 1] = st[j + 1] * wi + ki * v4.y; yi += st[j + 1] * r4.y;
                st[j + 2] = st[j + 2] * wi + ki * v4.z; yi += st[j + 2] * r4.z;
                st[j + 3] = st[j + 3] * wi + ki * v4.w; yi += st[j + 3] * r4.w;
            }
            yi += __shfl_xor(yi, 1);
            yi += __shfl_xor(yi, 2);
            if (q == 0) y[base + (size_t)(t0 + u) * C + i] = yi;
        }
    }
}

// z[m,:] = ( LN(y[m,:])*ln_g + ln_b + (sum_head r*k*r_k) * v ) * g
__global__ __launch_bounds__(256)
void ln_rkv_gate(const float* __restrict__ y, const float* __restrict__ r,
                 const float* __restrict__ k, const float* __restrict__ v,
                 const float* __restrict__ g, const float* __restrict__ r_k,
                 const float* __restrict__ lng, const float* __restrict__ lnb,
                 float* __restrict__ z, int C)
{
    const int m   = blockIdx.x;
    const int tid = threadIdx.x;
    const size_t base = (size_t)m * C;
    const int c = tid << 2;

    const float4 y4 = *(const float4*)&y[base + c];
    float s  = y4.x + y4.y + y4.z + y4.w;
    float ss = y4.x * y4.x + y4.y * y4.y + y4.z * y4.z + y4.w * y4.w;
#pragma unroll
    for (int o = 1; o < 64; o <<= 1) { s += __shfl_xor(s, o); ss += __shfl_xor(ss, o); }
    __shared__ float red[2][4];
    const int wid = tid >> 6, lid = tid & 63;
    if (lid == 0) { red[0][wid] = s; red[1][wid] = ss; }
    __syncthreads();
    s  = red[0][0] + red[0][1] + red[0][2] + red[0][3];
    ss = red[1][0] + red[1][1] + red[1][2] + red[1][3];
    const float mean = s / (float)C;
    const float var  = ss / (float)C - mean * mean;
    const float inv  = rsqrtf(var + 1e-5f);

    // rkv head partial: each thread's 4 elems are within one head (64 elems =
    // 16 threads/head); xor-reduce over the 16-lane group.
    const float4 r4  = *(const float4*)&r[base + c];
    const float4 k4  = *(const float4*)&k[base + c];
    const float4 rk4 = *(const float4*)&r_k[c];
    float p = r4.x * k4.x * rk4.x + r4.y * k4.y * rk4.y + r4.z * k4.z * rk4.z + r4.w * k4.w * rk4.w;
    p += __shfl_xor(p, 1); p += __shfl_xor(p, 2); p += __shfl_xor(p, 4); p += __shfl_xor(p, 8);

    const float4 v4 = *(const float4*)&v[base + c];
    const float4 g4 = *(const float4*)&g[base + c];
    const float4 lg = *(const float4*)&lng[c];
    const float4 lb = *(const float4*)&lnb[c];
    float4 res;
    res.x = ((y4.x - mean) * inv * lg.x + lb.x + p * v4.x) * g4.x;
    res.y = ((y4.y - mean) * inv * lg.y + lb.y + p * v4.y) * g4.y;
    res.z = ((y4.z - mean) * inv * lg.z + lb.z + p * v4.z) * g4.z;
    res.w = ((y4.w - mean) * inv * lg.w + lb.w + p * v4.w) * g4.w;
    *(float4*)&z[base + c] = res;
}

extern "C" void kernel_launch(void* const* d_in, const int* in_sizes, int n_in,
                              void* d_out, int out_size, void* d_ws, size_t ws_size,
                              hipStream_t stream)
{
    const float* x    = (const float*)d_in[0];
    const float* vfst = (const float*)d_in[1];
    const float* Wr   = (const float*)d_in[2];
    const float* Wk   = (const float*)d_in[3];
    const float* Wv   = (const float*)d_in[4];
    const float* Wo   = (const float*)d_in[5];
    const float* Wg1  = (const float*)d_in[6];
    const float* Wg2  = (const float*)d_in[7];
    const float* W1   = (const float*)d_in[8];
    const float* W2   = (const float*)d_in[9];
    const float* A1   = (const float*)d_in[10];
    const float* A2   = (const float*)d_in[11];
    const float* V1   = (const float*)d_in[12];
    const float* V2   = (const float*)d_in[13];
    const float* tm_r = (const float*)d_in[14];
    const float* tm_w = (const float*)d_in[15];
    const float* tm_k = (const float*)d_in[16];
    const float* tm_v = (const float*)d_in[17];
    const float* tm_a = (const float*)d_in[18];
    const float* tm_g = (const float*)d_in[19];
    const float* w0   = (const float*)d_in[20];
    const float* a0   = (const float*)d_in[21];
    const float* v0   = (const float*)d_in[22];
    /* d_in[23] = k_k (unused by reference) */
    const float* k_a  = (const float*)d_in[24];
    const float* r_k  = (const float*)d_in[25];
    const float* ln_g = (const float*)d_in[26];
    const float* ln_b = (const float*)d_in[27];
    float* out = (float*)d_out;

    const int Bn = 2, Tn = 2048, C = 1024, Hh = 16;
    const int M = Bn * Tn, K = C, N = C;
    const size_t S = (size_t)M * C;

    float* ws = (float*)d_ws;
    float* br = ws;            // r
    float* bk = ws + S;        // k
    float* bv = ws + 2 * S;    // v
    float* bw = ws + 3 * S;    // w
    float* bg = ws + 4 * S;    // g
    float* bt = ws + 5 * S;    // staging (reused), later y/z
    float* by = bt;

    dim3 grid(N / BN, M / BM);
    dim3 blk(256);

    // r, k, v
    gemm_nt<A_MIX, EP_STORE><<<grid, blk, 0, stream>>>(x, tm_r, Wr, br, nullptr, nullptr, M, K, N, Tn);
    gemm_nt<A_MIX, EP_STORE><<<grid, blk, 0, stream>>>(x, tm_k, Wk, bk, nullptr, nullptr, M, K, N, Tn);
    gemm_nt<A_MIX, EP_STORE><<<grid, blk, 0, stream>>>(x, tm_v, Wv, bv, nullptr, nullptr, M, K, N, Tn);
    // w = exp(-0.606531*sigmoid(w0 + tanh(xw@W1^T)@W2^T))
    gemm_nt<A_MIX, EP_TANH><<<grid, blk, 0, stream>>>(x, tm_w, W1, bt, nullptr, nullptr, M, K, N, Tn);
    gemm_nt<A_PLAIN, EP_W><<<grid, blk, 0, stream>>>(bt, nullptr, W2, bw, w0, nullptr, M, K, N, Tn);
    // a = sigmoid(a0 + (xa@A1^T)@A2^T); k *= 1+(a-1)*k_a   (in-place on k)
    gemm_nt<A_MIX, EP_STORE><<<grid, blk, 0, stream>>>(x, tm_a, A1, bt, nullptr, nullptr, M, K, N, Tn);
    gemm_nt<A_PLAIN, EP_AK><<<grid, blk, 0, stream>>>(bt, nullptr, A2, bk, a0, k_a, M, K, N, Tn);
    // g = sigmoid(xg@Wg1^T) @ Wg2^T
    gemm_nt<A_MIX, EP_SIGMOID><<<grid, blk, 0, stream>>>(x, tm_g, Wg1, bt, nullptr, nullptr, M, K, N, Tn);
    gemm_nt<A_PLAIN, EP_STORE><<<grid, blk, 0, stream>>>(bt, nullptr, Wg2, bg, nullptr, nullptr, M, K, N, Tn);
    // v += (v_first - v) * sigmoid(v0 + (xv@V1^T)@V2^T)   (in-place on v)
    gemm_nt<A_MIX, EP_STORE><<<grid, blk, 0, stream>>>(x, tm_v, V1, bt, nullptr, nullptr, M, K, N, Tn);
    gemm_nt<A_PLAIN, EP_VBLEND><<<grid, blk, 0, stream>>>(bt, nullptr, V2, bv, v0, vfst, M, K, N, Tn);
    // WKV7 scan -> y
    wkv7_scan<<<dim3(Bn * Hh * 4), dim3(64), 0, stream>>>(br, bw, bk, bv, by, Bn, Tn, Hh);
    // LN + rkv + gate -> z (in-place over y)
    ln_rkv_gate<<<dim3(M), dim3(256), 0, stream>>>(by, br, bk, bv, bg, r_k, ln_g, ln_b, by, C);
    // out = z @ Wo^T
    gemm_nt<A_PLAIN, EP_STORE><<<grid, blk, 0, stream>>>(by, nullptr, Wo, out, nullptr, nullptr, M, K, N, Tn);
}

// Round 2
// 844.024 us; speedup vs baseline: 2.8684x; 2.8684x over previous
//
#include <hip/hip_runtime.h>
#include <hip/hip_bf16.h>
#include <cmath>

// ---------------------------------------------------------------------------
// RWKV-7 TimeMixing. B=2, T=2048, C=1024, H=16, N=64, M=4096.
// FAST path (ws >= 216MB): bf16 MFMA GEMMs (w-path via bf16x2 split K=3072),
// j-split deep-pipelined scan, fused LN+rkv+gate (bf16 out).
// FALLBACK (ws < 216MB): round-1 fp32 path, known-good.
// ---------------------------------------------------------------------------

typedef unsigned short u16;
typedef __attribute__((ext_vector_type(8))) short short8;   // 8 x bf16 frag
typedef __attribute__((ext_vector_type(4))) float f32x4;

__device__ __forceinline__ float sigf(float x) { return 1.f / (1.f + expf(-x)); }
__device__ __forceinline__ u16 f2b(float f) {
    union { float f; unsigned int u; } v; v.f = f;
    unsigned int r = (v.u + 0x7FFFu + ((v.u >> 16) & 1u)) >> 16;
    return (u16)r;
}
__device__ __forceinline__ float b2f(u16 b) {
    union { unsigned int u; float f; } v; v.u = ((unsigned int)b) << 16;
    return v.f;
}

// ============================ FAST PATH ====================================

// ---- prep: 10 plain weights fp32 -> bf16 (1M elems each, contiguous dst) ----
struct P10 { const float* p[10]; };
__global__ __launch_bounds__(256)
void conv_w10(P10 src, u16* __restrict__ dst) {
    const int wi = blockIdx.x >> 10;                       // 1024 blocks/weight
    const int t  = (((blockIdx.x & 1023) << 8) | threadIdx.x) << 2;
    const float4 v = *(const float4*)&src.p[wi][t];
    ushort4 o; o.x = f2b(v.x); o.y = f2b(v.y); o.z = f2b(v.z); o.w = f2b(v.w);
    *(ushort4*)&dst[((size_t)wi << 20) + t] = o;
}

// ---- prep: W1,W2 -> K-concat split layout [hi, lo, hi] (N x 3C) ----
__global__ __launch_bounds__(256)
void conv_cat(const float* __restrict__ W1, const float* __restrict__ W2,
              u16* __restrict__ c1, u16* __restrict__ c2) {
    const int t = (blockIdx.x * 256 + threadIdx.x) << 2;   // over 1M elems
    const int n = t >> 10, c = t & 1023;
    const size_t rb = (size_t)n * 3072 + c;
#pragma unroll
    for (int wsel = 0; wsel < 2; ++wsel) {
        const float* W = wsel ? W2 : W1;
        u16* dc = wsel ? c2 : c1;
        const float4 v = *(const float4*)&W[t];
        ushort4 hi, lo;
        hi.x = f2b(v.x); lo.x = f2b(v.x - b2f(hi.x));
        hi.y = f2b(v.y); lo.y = f2b(v.y - b2f(hi.y));
        hi.z = f2b(v.z); lo.z = f2b(v.z - b2f(hi.z));
        hi.w = f2b(v.w); lo.w = f2b(v.w - b2f(hi.w));
        *(ushort4*)&dc[rb]        = hi;
        *(ushort4*)&dc[rb + 1024] = lo;
        *(ushort4*)&dc[rb + 2048] = hi;
    }
}

// ---- prep: token-shift mixes -> bf16 activations (+ w-path split cat) ----
__global__ __launch_bounds__(256)
void prep_act(const float* __restrict__ x,
              const float* __restrict__ tmr, const float* __restrict__ tmw,
              const float* __restrict__ tmk, const float* __restrict__ tmv,
              const float* __restrict__ tma, const float* __restrict__ tmg,
              u16* __restrict__ axr, u16* __restrict__ axk, u16* __restrict__ axv,
              u16* __restrict__ axa, u16* __restrict__ axg, u16* __restrict__ axw,
              int T) {
    const int t = (blockIdx.x * 256 + threadIdx.x) << 2;   // over 4M elems
    const int m = t >> 10, c = t & 1023;
    const float4 xc = *(const float4*)&x[t];
    float4 xp = make_float4(0.f, 0.f, 0.f, 0.f);
    if ((m % T) != 0) xp = *(const float4*)&x[t - 1024];
    const float4 d = make_float4(xp.x - xc.x, xp.y - xc.y, xp.z - xc.z, xp.w - xc.w);
#define MIX_STORE(tm, dstp)                                            \
    {   const float4 tc = *(const float4*)&tm[c];                      \
        ushort4 o;                                                     \
        o.x = f2b(xc.x + d.x * tc.x); o.y = f2b(xc.y + d.y * tc.y);    \
        o.z = f2b(xc.z + d.z * tc.z); o.w = f2b(xc.w + d.w * tc.w);    \
        *(ushort4*)&dstp[t] = o; }
    MIX_STORE(tmr, axr) MIX_STORE(tmk, axk) MIX_STORE(tmv, axv)
    MIX_STORE(tma, axa) MIX_STORE(tmg, axg)
#undef MIX_STORE
    {   // w path: split into cat layout [hi, hi, lo]
        const float4 tc = *(const float4*)&tmw[c];
        float4 v = make_float4(xc.x + d.x * tc.x, xc.y + d.y * tc.y,
                               xc.z + d.z * tc.z, xc.w + d.w * tc.w);
        ushort4 hi, lo;
        hi.x = f2b(v.x); lo.x = f2b(v.x - b2f(hi.x));
        hi.y = f2b(v.y); lo.y = f2b(v.y - b2f(hi.y));
        hi.z = f2b(v.z); lo.z = f2b(v.z - b2f(hi.z));
        hi.w = f2b(v.w); lo.w = f2b(v.w - b2f(hi.w));
        const size_t rb = (size_t)m * 3072 + c;
        *(ushort4*)&axw[rb]        = hi;
        *(ushort4*)&axw[rb + 1024] = hi;
        *(ushort4*)&axw[rb + 2048] = lo;
    }
}

// ---- bf16 MFMA NT-GEMM: O[m,n] = sum_k A[m,k]*B[n,k], 128x128 tile ----
#define TM 128
#define TN 128
#define TK 32
#define PK 40   // padded LDS row stride (bf16 elems) -> 80B, breaks conflicts

enum { FE_F32 = 0, FE_B16 = 1, FE_SIGB = 2, FE_TANHCAT = 3, FE_W = 4, FE_AK = 5, FE_VBLEND = 6 };

template<int EPI>
__global__ __launch_bounds__(256)
void mfma_nt(const u16* __restrict__ A, const u16* __restrict__ B,
             float* __restrict__ Of, u16* __restrict__ Ob,
             const float* __restrict__ bias, const float* __restrict__ extra,
             int M, int N, int K)
{
    __shared__ u16 As[TM * PK];
    __shared__ u16 Bs[TN * PK];
    const int t  = threadIdx.x;
    const int m0 = blockIdx.y * TM;
    const int n0 = blockIdx.x * TN;
    const int wv = t >> 6, ln = t & 63;
    const int wr = (wv >> 1) * 64;       // wave m-offset in tile
    const int wc = (wv & 1) * 64;        // wave n-offset in tile
    const int fr = ln & 15;              // fragment row (m or n within 16)
    const int fq = ln >> 4;              // quad -> k-group of 8
    const int srow = t >> 2;             // staging row 0..63
    const int sk   = (t & 3) << 3;       // staging k-offset (bf16 elems)

    f32x4 acc[4][4];
#pragma unroll
    for (int i = 0; i < 4; ++i)
#pragma unroll
        for (int j = 0; j < 4; ++j) {
            acc[i][j][0] = 0.f; acc[i][j][1] = 0.f; acc[i][j][2] = 0.f; acc[i][j][3] = 0.f;
        }

    // prologue loads for k0 = 0
    uint4 sa0 = *(const uint4*)&A[(size_t)(m0 + srow) * K + sk];
    uint4 sa1 = *(const uint4*)&A[(size_t)(m0 + srow + 64) * K + sk];
    uint4 sb0 = *(const uint4*)&B[(size_t)(n0 + srow) * K + sk];
    uint4 sb1 = *(const uint4*)&B[(size_t)(n0 + srow + 64) * K + sk];

    for (int k0 = 0; k0 < K; k0 += TK) {
        __syncthreads();   // prev iter's LDS reads done
        *(uint4*)&As[srow * PK + sk]        = sa0;
        *(uint4*)&As[(srow + 64) * PK + sk] = sa1;
        *(uint4*)&Bs[srow * PK + sk]        = sb0;
        *(uint4*)&Bs[(srow + 64) * PK + sk] = sb1;
        __syncthreads();
        if (k0 + TK < K) {   // prefetch next tile while MFMAs run
            const int kn = k0 + TK;
            sa0 = *(const uint4*)&A[(size_t)(m0 + srow) * K + kn + sk];
            sa1 = *(const uint4*)&A[(size_t)(m0 + srow + 64) * K + kn + sk];
            sb0 = *(const uint4*)&B[(size_t)(n0 + srow) * K + kn + sk];
            sb1 = *(const uint4*)&B[(size_t)(n0 + srow + 64) * K + kn + sk];
        }
        short8 af[4], bfr[4];
#pragma unroll
        for (int i = 0; i < 4; ++i) {
            af[i]  = *(const short8*)&As[(wr + i * 16 + fr) * PK + fq * 8];
            bfr[i] = *(const short8*)&Bs[(wc + i * 16 + fr) * PK + fq * 8];
        }
#pragma unroll
        for (int i = 0; i < 4; ++i)
#pragma unroll
            for (int j = 0; j < 4; ++j)
                acc[i][j] = __builtin_amdgcn_mfma_f32_16x16x32_bf16(af[i], bfr[j], acc[i][j], 0, 0, 0);
    }

    // epilogue: lane holds D[row = fq*4+reg][col = fr] per 16x16 tile
#pragma unroll
    for (int i = 0; i < 4; ++i) {
#pragma unroll
        for (int r = 0; r < 4; ++r) {
            const int m = m0 + wr + i * 16 + fq * 4 + r;
            const size_t rowf = (size_t)m * N;
#pragma unroll
            for (int j = 0; j < 4; ++j) {
                const int n = n0 + wc + j * 16 + fr;
                const float val = acc[i][j][r];
                if (EPI == FE_F32) {
                    Of[rowf + n] = val;
                } else if (EPI == FE_B16) {
                    Ob[rowf + n] = f2b(val);
                } else if (EPI == FE_SIGB) {
                    Ob[rowf + n] = f2b(sigf(val));
                } else if (EPI == FE_TANHCAT) {
                    const float tv = tanhf(val);
                    const u16 hi = f2b(tv);
                    const u16 lo = f2b(tv - b2f(hi));
                    const size_t rc = (size_t)m * (3 * N);
                    Ob[rc + n] = hi; Ob[rc + N + n] = hi; Ob[rc + 2 * N + n] = lo;
                } else if (EPI == FE_W) {
                    Of[rowf + n] = expf(-0.606531f * sigf(bias[n] + val));
                } else if (EPI == FE_AK) {
                    const float kv = Of[rowf + n];
                    Of[rowf + n] = kv * (1.f + (sigf(bias[n] + val) - 1.f) * extra[n]);
                } else { // FE_VBLEND
                    const float vv = Of[rowf + n];
                    const float s  = sigf(bias[n] + val);
                    Of[rowf + n] = vv + (extra[rowf + n] - vv) * s;
                }
            }
        }
    }
}

// ---- WKV7 scan, i-split 4 x j-split 4 = 512 blocks, 32-step chunks ----
#define SCHUNK 32
__global__ __launch_bounds__(64)
void wkv7_scan_fast(const float* __restrict__ r, const float* __restrict__ w,
                    const float* __restrict__ k, const float* __restrict__ v,
                    float* __restrict__ yp0, float* __restrict__ yp1,
                    float* __restrict__ yp2, float* __restrict__ yp3,
                    int Bn, int Tn, int Hn)
{
    const int blk = blockIdx.x;           // ((b*H + h)*4 + is)*4 + js
    const int js  = blk & 3;
    const int is  = (blk >> 2) & 3;
    const int h   = (blk >> 4) % Hn;
    const int b   = blk / (16 * Hn);
    const int ln  = threadIdx.x;
    const int il  = ln >> 2, jq = ln & 3;
    const int i0  = is * 16, j0 = js * 16;
    const int C   = Hn * 64;
    const size_t hbase = (size_t)b * Tn * C + h * 64;
    float* yp = (js == 0) ? yp0 : (js == 1) ? yp1 : (js == 2) ? yp2 : yp3;

    const int arr = ln >> 4;              // 0:v 1:r 2:w 3:k
    const int idx = ln & 15;
    const float* src = (arr == 0) ? v : (arr == 1) ? r : (arr == 2) ? w : k;
    const int off = (arr < 2 ? j0 : i0) + idx;

    __shared__ float st4[4][SCHUNK][16];

    float st[4] = {0.f, 0.f, 0.f, 0.f};
    float cur[SCHUNK];
#pragma unroll
    for (int s = 0; s < SCHUNK; ++s) cur[s] = src[hbase + (size_t)s * C + off];

    const int NC = Tn / SCHUNK;
    for (int c = 0; c < NC; ++c) {
        __syncthreads();
#pragma unroll
        for (int s = 0; s < SCHUNK; ++s) st4[arr][s][idx] = cur[s];
        __syncthreads();
        if (c + 1 < NC) {
            const size_t nb = hbase + (size_t)(c + 1) * SCHUNK * C;
#pragma unroll
            for (int s = 0; s < SCHUNK; ++s) cur[s] = src[nb + (size_t)s * C + off];
        }
        const size_t ybase = hbase + (size_t)c * SCHUNK * C + i0 + il;
#pragma unroll
        for (int s = 0; s < SCHUNK; ++s) {
            const float wi = st4[2][s][il];
            const float ki = st4[3][s][il];
            const float4 v4 = *(const float4*)&st4[0][s][jq * 4];
            const float4 r4 = *(const float4*)&st4[1][s][jq * 4];
            st[0] = st[0] * wi + ki * v4.x;
            st[1] = st[1] * wi + ki * v4.y;
            st[2] = st[2] * wi + ki * v4.z;
            st[3] = st[3] * wi + ki * v4.w;
            float yi = st[0] * r4.x + st[1] * r4.y + st[2] * r4.z + st[3] * r4.w;
            yi += __shfl_xor(yi, 1);
            yi += __shfl_xor(yi, 2);
            if (jq == 0) yp[ybase + (size_t)s * C] = yi;
        }
    }
}

// ---- fused LN + rkv + gate, y = sum of 4 partials, bf16 out ----
__global__ __launch_bounds__(256)
void ln_rkv_gate_fast(const float* __restrict__ yp0, const float* __restrict__ yp1,
                      const float* __restrict__ yp2, const float* __restrict__ yp3,
                      const float* __restrict__ r, const float* __restrict__ k,
                      const float* __restrict__ v, const float* __restrict__ g,
                      const float* __restrict__ r_k, const float* __restrict__ lng,
                      const float* __restrict__ lnb, u16* __restrict__ z, int C)
{
    const int m   = blockIdx.x;
    const int tid = threadIdx.x;
    const size_t base = (size_t)m * C;
    const int c = tid << 2;

    const float4 a = *(const float4*)&yp0[base + c];
    const float4 b4 = *(const float4*)&yp1[base + c];
    const float4 c4 = *(const float4*)&yp2[base + c];
    const float4 d4 = *(const float4*)&yp3[base + c];
    float4 y4;
    y4.x = a.x + b4.x + c4.x + d4.x;
    y4.y = a.y + b4.y + c4.y + d4.y;
    y4.z = a.z + b4.z + c4.z + d4.z;
    y4.w = a.w + b4.w + c4.w + d4.w;

    float s  = y4.x + y4.y + y4.z + y4.w;
    float ss = y4.x * y4.x + y4.y * y4.y + y4.z * y4.z + y4.w * y4.w;
#pragma unroll
    for (int o = 1; o < 64; o <<= 1) { s += __shfl_xor(s, o); ss += __shfl_xor(ss, o); }
    __shared__ float red[2][4];
    const int wid = tid >> 6, lid = tid & 63;
    if (lid == 0) { red[0][wid] = s; red[1][wid] = ss; }
    __syncthreads();
    s  = red[0][0] + red[0][1] + red[0][2] + red[0][3];
    ss = red[1][0] + red[1][1] + red[1][2] + red[1][3];
    const float mean = s / (float)C;
    const float var  = ss / (float)C - mean * mean;
    const float inv  = rsqrtf(var + 1e-5f);

    const float4 r4  = *(const float4*)&r[base + c];
    const float4 k4  = *(const float4*)&k[base + c];
    const float4 rk4 = *(const float4*)&r_k[c];
    float p = r4.x * k4.x * rk4.x + r4.y * k4.y * rk4.y + r4.z * k4.z * rk4.z + r4.w * k4.w * rk4.w;
    p += __shfl_xor(p, 1); p += __shfl_xor(p, 2); p += __shfl_xor(p, 4); p += __shfl_xor(p, 8);

    const float4 v4 = *(const float4*)&v[base + c];
    const float4 g4 = *(const float4*)&g[base + c];
    const float4 lg = *(const float4*)&lng[c];
    const float4 lb = *(const float4*)&lnb[c];
    ushort4 res;
    res.x = f2b(((y4.x - mean) * inv * lg.x + lb.x + p * v4.x) * g4.x);
    res.y = f2b(((y4.y - mean) * inv * lg.y + lb.y + p * v4.y) * g4.y);
    res.z = f2b(((y4.z - mean) * inv * lg.z + lb.z + p * v4.z) * g4.z);
    res.w = f2b(((y4.w - mean) * inv * lg.w + lb.w + p * v4.w) * g4.w);
    *(ushort4*)&z[base + c] = res;
}

// ============================ FALLBACK (round-1 fp32) =======================

#define BM 64
#define BN 64
#define BK 32
enum { A_PLAIN = 0, A_MIX = 1 };
enum { EP_STORE = 0, EP_TANH = 1, EP_W = 2, EP_SIGMOID = 3, EP_AK = 4, EP_VBLEND = 5 };

template<int AMODE, int EPI>
__global__ __launch_bounds__(256)
void gemm_nt(const float* __restrict__ A, const float* __restrict__ tm,
             const float* __restrict__ W, float* __restrict__ O,
             const float* __restrict__ bias, const float* __restrict__ extra,
             int M, int K, int N, int Tdim)
{
    __shared__ float As[BK][BM + 4];
    __shared__ float Bs[BK][BN + 4];
    const int tid  = threadIdx.x;
    const int m0   = blockIdx.y * BM;
    const int n0   = blockIdx.x * BN;
    const int lrow = tid >> 3;
    const int lcol = (tid & 7) << 2;
    const int ty   = tid >> 4;
    const int tx   = tid & 15;
    float acc[4][4] = {{0.f}};

    for (int k0 = 0; k0 < K; k0 += BK) {
#pragma unroll
        for (int rr = 0; rr < 2; ++rr) {
            const int row = lrow + rr * 32;
            const int m   = m0 + row;
            float4 av;
            if (AMODE == A_MIX) {
                const float4 xc = *(const float4*)&A[(size_t)m * K + k0 + lcol];
                float4 xp = make_float4(0.f, 0.f, 0.f, 0.f);
                if ((m % Tdim) != 0)
                    xp = *(const float4*)&A[(size_t)(m - 1) * K + k0 + lcol];
                const float4 tc = *(const float4*)&tm[k0 + lcol];
                av.x = xc.x + (xp.x - xc.x) * tc.x;
                av.y = xc.y + (xp.y - xc.y) * tc.y;
                av.z = xc.z + (xp.z - xc.z) * tc.z;
                av.w = xc.w + (xp.w - xc.w) * tc.w;
            } else {
                av = *(const float4*)&A[(size_t)m * K + k0 + lcol];
            }
            As[lcol + 0][row] = av.x; As[lcol + 1][row] = av.y;
            As[lcol + 2][row] = av.z; As[lcol + 3][row] = av.w;
            const float4 bv = *(const float4*)&W[(size_t)(n0 + row) * K + k0 + lcol];
            Bs[lcol + 0][row] = bv.x; Bs[lcol + 1][row] = bv.y;
            Bs[lcol + 2][row] = bv.z; Bs[lcol + 3][row] = bv.w;
        }
        __syncthreads();
#pragma unroll
        for (int kk = 0; kk < BK; ++kk) {
            const float4 a4 = *(const float4*)&As[kk][ty << 2];
            const float4 b4 = *(const float4*)&Bs[kk][tx << 2];
            acc[0][0] += a4.x * b4.x; acc[0][1] += a4.x * b4.y; acc[0][2] += a4.x * b4.z; acc[0][3] += a4.x * b4.w;
            acc[1][0] += a4.y * b4.x; acc[1][1] += a4.y * b4.y; acc[1][2] += a4.y * b4.z; acc[1][3] += a4.y * b4.w;
            acc[2][0] += a4.z * b4.x; acc[2][1] += a4.z * b4.y; acc[2][2] += a4.z * b4.z; acc[2][3] += a4.z * b4.w;
            acc[3][0] += a4.w * b4.x; acc[3][1] += a4.w * b4.y; acc[3][2] += a4.w * b4.z; acc[3][3] += a4.w * b4.w;
        }
        __syncthreads();
    }

#pragma unroll
    for (int ii = 0; ii < 4; ++ii) {
        const int m = m0 + (ty << 2) + ii;
        const int n = n0 + (tx << 2);
        const size_t o = (size_t)m * N + n;
        const float a0v = acc[ii][0], a1v = acc[ii][1], a2v = acc[ii][2], a3v = acc[ii][3];
        float4 res;
        if (EPI == EP_STORE) {
            res = make_float4(a0v, a1v, a2v, a3v);
        } else if (EPI == EP_TANH) {
            res = make_float4(tanhf(a0v), tanhf(a1v), tanhf(a2v), tanhf(a3v));
        } else if (EPI == EP_SIGMOID) {
            res = make_float4(sigf(a0v), sigf(a1v), sigf(a2v), sigf(a3v));
        } else if (EPI == EP_W) {
            const float4 b = *(const float4*)&bias[n];
            res.x = expf(-0.606531f * sigf(b.x + a0v));
            res.y = expf(-0.606531f * sigf(b.y + a1v));
            res.z = expf(-0.606531f * sigf(b.z + a2v));
            res.w = expf(-0.606531f * sigf(b.w + a3v));
        } else if (EPI == EP_AK) {
            const float4 b  = *(const float4*)&bias[n];
            const float4 ka = *(const float4*)&extra[n];
            const float4 kv = *(const float4*)&O[o];
            res.x = kv.x * (1.f + (sigf(b.x + a0v) - 1.f) * ka.x);
            res.y = kv.y * (1.f + (sigf(b.y + a1v) - 1.f) * ka.y);
            res.z = kv.z * (1.f + (sigf(b.z + a2v) - 1.f) * ka.z);
            res.w = kv.w * (1.f + (sigf(b.w + a3v) - 1.f) * ka.w);
        } else {
            const float4 b  = *(const float4*)&bias[n];
            const float4 vf = *(const float4*)&extra[o];
            const float4 vv = *(const float4*)&O[o];
            float sx;
            sx = sigf(b.x + a0v); res.x = vv.x + (vf.x - vv.x) * sx;
            sx = sigf(b.y + a1v); res.y = vv.y + (vf.y - vv.y) * sx;
            sx = sigf(b.z + a2v); res.z = vv.z + (vf.z - vv.z) * sx;
            sx = sigf(b.w + a3v); res.w = vv.w + (vf.w - vv.w) * sx;
        }
        *(float4*)&O[o] = res;
    }
}

__global__ __launch_bounds__(64)
void wkv7_scan(const float* __restrict__ r, const float* __restrict__ w,
               const float* __restrict__ k, const float* __restrict__ v,
               float* __restrict__ y, int Bn, int Tn, int Hn)
{
    const int blk  = blockIdx.x;
    const int s    = blk & 3;
    const int h    = (blk >> 2) % Hn;
    const int b    = blk / (4 * Hn);
    const int lane = threadIdx.x;
    const int il   = lane >> 2;
    const int q    = lane & 3;
    const int i    = s * 16 + il;
    const int C    = Hn * 64;
    const size_t base = (size_t)b * Tn * C + h * 64;

    float st[16];
#pragma unroll
    for (int j = 0; j < 16; ++j) st[j] = 0.f;

    __shared__ float vs[4][64];
    __shared__ float rs[4][64];

    for (int t0 = 0; t0 < Tn; t0 += 4) {
        float vl[4], rl[4], wl[4], kl[4];
#pragma unroll
        for (int u = 0; u < 4; ++u) {
            const size_t off = base + (size_t)(t0 + u) * C;
            vl[u] = v[off + lane]; rl[u] = r[off + lane];
            wl[u] = w[off + i];    kl[u] = k[off + i];
        }
        __syncthreads();
#pragma unroll
        for (int u = 0; u < 4; ++u) { vs[u][lane] = vl[u]; rs[u][lane] = rl[u]; }
        __syncthreads();
#pragma unroll
        for (int u = 0; u < 4; ++u) {
            const float wi = wl[u], ki = kl[u];
            float yi = 0.f;
#pragma unroll
            for (int jg = 0; jg < 4; ++jg) {
                const float4 v4 = *(const float4*)&vs[u][q * 16 + jg * 4];
                const float4 r4 = *(const float4*)&rs[u][q * 16 + jg * 4];
                const int j = jg * 4;
                st[j + 0] = st[j + 0] * wi + ki * v4.x; yi += st[j + 0] * r4.x;
                st[j + 1] = st[j + 1] * wi + ki * v4.y; yi += st[j + 1] * r4.y;
                st[j + 2] = st[j + 2] * wi + ki * v4.z; yi += st[j + 2] * r4.z;
                st[j + 3] = st[j + 3] * wi + ki * v4.w; yi += st[j + 3] * r4.w;
            }
            yi += __shfl_xor(yi, 1);
            yi += __shfl_xor(yi, 2);
            if (q == 0) y[base + (size_t)(t0 + u) * C + i] = yi;
        }
    }
}

__global__ __launch_bounds__(256)
void ln_rkv_gate(const float* __restrict__ y, const float* __restrict__ r,
                 const float* __restrict__ k, const float* __restrict__ v,
                 const float* __restrict__ g, const float* __restrict__ r_k,
                 const float* __restrict__ lng, const float* __restrict__ lnb,
                 float* __restrict__ z, int C)
{
    const int m   = blockIdx.x;
    const int tid = threadIdx.x;
    const size_t base = (size_t)m * C;
    const int c = tid << 2;

    const float4 y4 = *(const float4*)&y[base + c];
    float s  = y4.x + y4.y + y4.z + y4.w;
    float ss = y4.x * y4.x + y4.y * y4.y + y4.z * y4.z + y4.w * y4.w;
#pragma unroll
    for (int o = 1; o < 64; o <<= 1) { s += __shfl_xor(s, o); ss += __shfl_xor(ss, o); }
    __shared__ float red[2][4];
    const int wid = tid >> 6, lid = tid & 63;
    if (lid == 0) { red[0][wid] = s; red[1][wid] = ss; }
    __syncthreads();
    s  = red[0][0] + red[0][1] + red[0][2] + red[0][3];
    ss = red[1][0] + red[1][1] + red[1][2] + red[1][3];
    const float mean = s / (float)C;
    const float var  = ss / (float)C - mean * mean;
    const float inv  = rsqrtf(var + 1e-5f);

    const float4 r4  = *(const float4*)&r[base + c];
    const float4 k4  = *(const float4*)&k[base + c];
    const float4 rk4 = *(const float4*)&r_k[c];
    float p = r4.x * k4.x * rk4.x + r4.y * k4.y * rk4.y + r4.z * k4.z * rk4.z + r4.w * k4.w * rk4.w;
    p += __shfl_xor(p, 1); p += __shfl_xor(p, 2); p += __shfl_xor(p, 4); p += __shfl_xor(p, 8);

    const float4 v4 = *(const float4*)&v[base + c];
    const float4 g4 = *(const float4*)&g[base + c];
    const float4 lg = *(const float4*)&lng[c];
    const float4 lb = *(const float4*)&lnb[c];
    float4 res;
    res.x = ((y4.x - mean) * inv * lg.x + lb.x + p * v4.x) * g4.x;
    res.y = ((y4.y - mean) * inv * lg.y + lb.y + p * v4.y) * g4.y;
    res.z = ((y4.z - mean) * inv * lg.z + lb.z + p * v4.z) * g4.z;
    res.w = ((y4.w - mean) * inv * lg.w + lb.w + p * v4.w) * g4.w;
    *(float4*)&z[base + c] = res;
}

// ============================ LAUNCH ========================================

extern "C" void kernel_launch(void* const* d_in, const int* in_sizes, int n_in,
                              void* d_out, int out_size, void* d_ws, size_t ws_size,
                              hipStream_t stream)
{
    const float* x    = (const float*)d_in[0];
    const float* vfst = (const float*)d_in[1];
    const float* Wr   = (const float*)d_in[2];
    const float* Wk   = (const float*)d_in[3];
    const float* Wv   = (const float*)d_in[4];
    const float* Wo   = (const float*)d_in[5];
    const float* Wg1  = (const float*)d_in[6];
    const float* Wg2  = (const float*)d_in[7];
    const float* W1   = (const float*)d_in[8];
    const float* W2   = (const float*)d_in[9];
    const float* A1   = (const float*)d_in[10];
    const float* A2   = (const float*)d_in[11];
    const float* V1   = (const float*)d_in[12];
    const float* V2   = (const float*)d_in[13];
    const float* tm_r = (const float*)d_in[14];
    const float* tm_w = (const float*)d_in[15];
    const float* tm_k = (const float*)d_in[16];
    const float* tm_v = (const float*)d_in[17];
    const float* tm_a = (const float*)d_in[18];
    const float* tm_g = (const float*)d_in[19];
    const float* w0   = (const float*)d_in[20];
    const float* a0   = (const float*)d_in[21];
    const float* v0   = (const float*)d_in[22];
    const float* k_a  = (const float*)d_in[24];
    const float* r_k  = (const float*)d_in[25];
    const float* ln_g = (const float*)d_in[26];
    const float* ln_b = (const float*)d_in[27];
    float* out = (float*)d_out;

    const int Bn = 2, Tn = 2048, C = 1024, Hh = 16;
    const int M = Bn * Tn, K = C, N = C;
    const size_t MBy = (size_t)1 << 20;
    const size_t NEED = 216 * MBy;

    if (ws_size >= NEED) {
        // -------- fast path --------
        unsigned char* w8 = (unsigned char*)d_ws;
        u16* wb    = (u16*)(w8 + 0);          // 10 bf16 weights, 2MB each
        u16* w1cat = (u16*)(w8 + 20 * MBy);
        u16* w2cat = (u16*)(w8 + 26 * MBy);
        u16* axr   = (u16*)(w8 + 32 * MBy);
        u16* axk   = (u16*)(w8 + 40 * MBy);
        u16* axv   = (u16*)(w8 + 48 * MBy);
        u16* axa   = (u16*)(w8 + 56 * MBy);
        u16* axg   = (u16*)(w8 + 64 * MBy);
        u16* axw   = (u16*)(w8 + 72 * MBy);   // 24MB cat
        u16* btw   = (u16*)(w8 + 96 * MBy);   // 24MB cat
        u16* bt1   = (u16*)(w8 + 120 * MBy);  // 8MB
        float* br  = (float*)(w8 + 128 * MBy);
        float* bk  = (float*)(w8 + 144 * MBy);
        float* bv  = (float*)(w8 + 160 * MBy);
        float* bw  = (float*)(w8 + 176 * MBy);
        float* bg  = (float*)(w8 + 192 * MBy);
        u16* bz    = (u16*)(w8 + 208 * MBy);
        float* yp0 = (float*)(w8 + 32 * MBy);   // alias axr+axk (dead by scan)
        float* yp1 = (float*)(w8 + 72 * MBy);   // alias axw/btw (dead by scan)
        float* yp2 = (float*)(w8 + 88 * MBy);
        float* yp3 = (float*)(w8 + 104 * MBy);

        u16* wWr = wb;             u16* wWk = wb + (1u << 20);
        u16* wWv = wb + (2u << 20); u16* wWo = wb + (3u << 20);
        u16* wWg1 = wb + (4u << 20); u16* wWg2 = wb + (5u << 20);
        u16* wA1 = wb + (6u << 20); u16* wA2 = wb + (7u << 20);
        u16* wV1 = wb + (8u << 20); u16* wV2 = wb + (9u << 20);

        P10 p10;
        p10.p[0] = Wr;  p10.p[1] = Wk;  p10.p[2] = Wv;  p10.p[3] = Wo;
        p10.p[4] = Wg1; p10.p[5] = Wg2; p10.p[6] = A1;  p10.p[7] = A2;
        p10.p[8] = V1;  p10.p[9] = V2;

        conv_w10<<<dim3(10240), dim3(256), 0, stream>>>(p10, wb);
        conv_cat<<<dim3(1024), dim3(256), 0, stream>>>(W1, W2, w1cat, w2cat);
        prep_act<<<dim3(4096), dim3(256), 0, stream>>>(x, tm_r, tm_w, tm_k, tm_v, tm_a, tm_g,
                                                       axr, axk, axv, axa, axg, axw, Tn);

        dim3 gg(N / TN, M / TM);   // (8, 32)
        dim3 gb(256);
        // r, k, v
        mfma_nt<FE_F32><<<gg, gb, 0, stream>>>(axr, wWr, br, nullptr, nullptr, nullptr, M, N, K);
        mfma_nt<FE_F32><<<gg, gb, 0, stream>>>(axk, wWk, bk, nullptr, nullptr, nullptr, M, N, K);
        mfma_nt<FE_F32><<<gg, gb, 0, stream>>>(axv, wWv, bv, nullptr, nullptr, nullptr, M, N, K);
        // w path (split GEMMs, K=3072)
        mfma_nt<FE_TANHCAT><<<gg, gb, 0, stream>>>(axw, w1cat, nullptr, btw, nullptr, nullptr, M, N, 3 * K);
        mfma_nt<FE_W><<<gg, gb, 0, stream>>>(btw, w2cat, bw, nullptr, w0, nullptr, M, N, 3 * K);
        // a path: a1 then k update
        mfma_nt<FE_B16><<<gg, gb, 0, stream>>>(axa, wA1, nullptr, bt1, nullptr, nullptr, M, N, K);
        mfma_nt<FE_AK><<<gg, gb, 0, stream>>>(bt1, wA2, bk, nullptr, a0, k_a, M, N, K);
        // g path
        mfma_nt<FE_SIGB><<<gg, gb, 0, stream>>>(axg, wWg1, nullptr, bt1, nullptr, nullptr, M, N, K);
        mfma_nt<FE_F32><<<gg, gb, 0, stream>>>(bt1, wWg2, bg, nullptr, nullptr, nullptr, M, N, K);
        // v blend path
        mfma_nt<FE_B16><<<gg, gb, 0, stream>>>(axv, wV1, nullptr, bt1, nullptr, nullptr, M, N, K);
        mfma_nt<FE_VBLEND><<<gg, gb, 0, stream>>>(bt1, wV2, bv, nullptr, v0, vfst, M, N, K);
        // scan -> 4 y-partials
        wkv7_scan_fast<<<dim3(Bn * Hh * 16), dim3(64), 0, stream>>>(br, bw, bk, bv,
                                                                    yp0, yp1, yp2, yp3, Bn, Tn, Hh);
        // LN + rkv + gate -> bz (bf16)
        ln_rkv_gate_fast<<<dim3(M), dim3(256), 0, stream>>>(yp0, yp1, yp2, yp3,
                                                            br, bk, bv, bg, r_k, ln_g, ln_b, bz, C);
        // out = z @ Wo^T
        mfma_nt<FE_F32><<<gg, gb, 0, stream>>>(bz, wWo, out, nullptr, nullptr, nullptr, M, N, K);
        return;
    }

    // -------- fallback: round-1 fp32 path (96MB ws) --------
    const size_t S = (size_t)M * C;
    float* ws = (float*)d_ws;
    float* br = ws;
    float* bk = ws + S;
    float* bv = ws + 2 * S;
    float* bw = ws + 3 * S;
    float* bg = ws + 4 * S;
    float* bt = ws + 5 * S;
    float* by = bt;

    dim3 grid(N / BN, M / BM);
    dim3 blk(256);

    gemm_nt<A_MIX, EP_STORE><<<grid, blk, 0, stream>>>(x, tm_r, Wr, br, nullptr, nullptr, M, K, N, Tn);
    gemm_nt<A_MIX, EP_STORE><<<grid, blk, 0, stream>>>(x, tm_k, Wk, bk, nullptr, nullptr, M, K, N, Tn);
    gemm_nt<A_MIX, EP_STORE><<<grid, blk, 0, stream>>>(x, tm_v, Wv, bv, nullptr, nullptr, M, K, N, Tn);
    gemm_nt<A_MIX, EP_TANH><<<grid, blk, 0, stream>>>(x, tm_w, W1, bt, nullptr, nullptr, M, K, N, Tn);
    gemm_nt<A_PLAIN, EP_W><<<grid, blk, 0, stream>>>(bt, nullptr, W2, bw, w0, nullptr, M, K, N, Tn);
    gemm_nt<A_MIX, EP_STORE><<<grid, blk, 0, stream>>>(x, tm_a, A1, bt, nullptr, nullptr, M, K, N, Tn);
    gemm_nt<A_PLAIN, EP_AK><<<grid, blk, 0, stream>>>(bt, nullptr, A2, bk, a0, k_a, M, K, N, Tn);
    gemm_nt<A_MIX, EP_SIGMOID><<<grid, blk, 0, stream>>>(x, tm_g, Wg1, bt, nullptr, nullptr, M, K, N, Tn);
    gemm_nt<A_PLAIN, EP_STORE><<<grid, blk, 0, stream>>>(bt, nullptr, Wg2, bg, nullptr, nullptr, M, K, N, Tn);
    gemm_nt<A_MIX, EP_STORE><<<grid, blk, 0, stream>>>(x, tm_v, V1, bt, nullptr, nullptr, M, K, N, Tn);
    gemm_nt<A_PLAIN, EP_VBLEND><<<grid, blk, 0, stream>>>(bt, nullptr, V2, bv, v0, vfst, M, K, N, Tn);
    wkv7_scan<<<dim3(Bn * Hh * 4), dim3(64), 0, stream>>>(br, bw, bk, bv, by, Bn, Tn, Hh);
    ln_rkv_gate<<<dim3(M), dim3(256), 0, stream>>>(by, br, bk, bv, bg, r_k, ln_g, ln_b, by, C);
    gemm_nt<A_PLAIN, EP_STORE><<<grid, blk, 0, stream>>>(by, nullptr, Wo, out, nullptr, nullptr, M, K, N, Tn);
}

// Round 3
// 715.190 us; speedup vs baseline: 3.3851x; 1.1801x over previous
//
#include <hip/hip_runtime.h>
#include <hip/hip_bf16.h>
#include <cmath>

// ---------------------------------------------------------------------------
// RWKV-7 TimeMixing. B=2, T=2048, C=1024, H=16, N=64, M=4096.
// FAST path (ws >= 204MB):
//   - bf16 MFMA GEMMs batched into 2 dependency stages (job-table dispatch)
//   - w-path in bf16x2 split precision: A-cat [hi|lo] x W-cat [hi|hi], K=2048
//   - chunked WKV7 scan (exact linear-state decomposition):
//       pass1: 16 chunks x 32 heads x 4 i-splits from zero state (parallel)
//       pass2: 16-step boundary-state recurrence
//       pass3: y += A_t (*) (S0 . r_t) correction
//   - fused LN + rkv + gate -> bf16, final Wo GEMM
// FALLBACK (ws < 204MB): round-1 fp32 path, known-good.
// ---------------------------------------------------------------------------

typedef unsigned short u16;
typedef __attribute__((ext_vector_type(8))) short short8;   // 8 x bf16 frag
typedef __attribute__((ext_vector_type(4))) float f32x4;

#define NDIM 1024

__device__ __forceinline__ float sigf(float x) { return 1.f / (1.f + expf(-x)); }
__device__ __forceinline__ u16 f2b(float f) {
    union { float f; unsigned int u; } v; v.f = f;
    unsigned int r = (v.u + 0x7FFFu + ((v.u >> 16) & 1u)) >> 16;
    return (u16)r;
}
__device__ __forceinline__ float b2f(u16 b) {
    union { unsigned int u; float f; } v; v.u = ((unsigned int)b) << 16;
    return v.f;
}

// ============================ FAST PATH ====================================

// ---- prep: 10 plain weights fp32 -> bf16 ----
struct P10 { const float* p[10]; };
__global__ __launch_bounds__(256)
void conv_w10(P10 src, u16* __restrict__ dst) {
    const int wi = blockIdx.x >> 10;
    const int t  = (((blockIdx.x & 1023) << 8) | threadIdx.x) << 2;
    const float4 v = *(const float4*)&src.p[wi][t];
    ushort4 o; o.x = f2b(v.x); o.y = f2b(v.y); o.z = f2b(v.z); o.w = f2b(v.w);
    *(ushort4*)&dst[((size_t)wi << 20) + t] = o;
}

// ---- prep: W1,W2 -> [hi|hi] duplicated cat layout (N x 2C) ----
__global__ __launch_bounds__(256)
void conv_cat2(const float* __restrict__ W1, const float* __restrict__ W2,
               u16* __restrict__ c1, u16* __restrict__ c2) {
    const int t = (blockIdx.x * 256 + threadIdx.x) << 2;   // over 1M elems
    const int n = t >> 10, c = t & 1023;
    const size_t rb = (size_t)n * 2048 + c;
#pragma unroll
    for (int wsel = 0; wsel < 2; ++wsel) {
        const float* W = wsel ? W2 : W1;
        u16* dc = wsel ? c2 : c1;
        const float4 v = *(const float4*)&W[t];
        ushort4 hi;
        hi.x = f2b(v.x); hi.y = f2b(v.y); hi.z = f2b(v.z); hi.w = f2b(v.w);
        *(ushort4*)&dc[rb]        = hi;
        *(ushort4*)&dc[rb + 1024] = hi;
    }
}

// ---- prep: token-shift mixes -> bf16 activations (w-path [hi|lo] cat) ----
__global__ __launch_bounds__(256)
void prep_act(const float* __restrict__ x,
              const float* __restrict__ tmr, const float* __restrict__ tmw,
              const float* __restrict__ tmk, const float* __restrict__ tmv,
              const float* __restrict__ tma, const float* __restrict__ tmg,
              u16* __restrict__ axr, u16* __restrict__ axk, u16* __restrict__ axv,
              u16* __restrict__ axa, u16* __restrict__ axg, u16* __restrict__ axw,
              int T) {
    const int t = (blockIdx.x * 256 + threadIdx.x) << 2;
    const int m = t >> 10, c = t & 1023;
    const float4 xc = *(const float4*)&x[t];
    float4 xp = make_float4(0.f, 0.f, 0.f, 0.f);
    if ((m % T) != 0) xp = *(const float4*)&x[t - 1024];
    const float4 d = make_float4(xp.x - xc.x, xp.y - xc.y, xp.z - xc.z, xp.w - xc.w);
#define MIX_STORE(tm, dstp)                                            \
    {   const float4 tc = *(const float4*)&tm[c];                      \
        ushort4 o;                                                     \
        o.x = f2b(xc.x + d.x * tc.x); o.y = f2b(xc.y + d.y * tc.y);    \
        o.z = f2b(xc.z + d.z * tc.z); o.w = f2b(xc.w + d.w * tc.w);    \
        *(ushort4*)&dstp[t] = o; }
    MIX_STORE(tmr, axr) MIX_STORE(tmk, axk) MIX_STORE(tmv, axv)
    MIX_STORE(tma, axa) MIX_STORE(tmg, axg)
#undef MIX_STORE
    {   // w path: [hi | lo]
        const float4 tc = *(const float4*)&tmw[c];
        float4 v = make_float4(xc.x + d.x * tc.x, xc.y + d.y * tc.y,
                               xc.z + d.z * tc.z, xc.w + d.w * tc.w);
        ushort4 hi, lo;
        hi.x = f2b(v.x); lo.x = f2b(v.x - b2f(hi.x));
        hi.y = f2b(v.y); lo.y = f2b(v.y - b2f(hi.y));
        hi.z = f2b(v.z); lo.z = f2b(v.z - b2f(hi.z));
        hi.w = f2b(v.w); lo.w = f2b(v.w - b2f(hi.w));
        const size_t rb = (size_t)m * 2048 + c;
        *(ushort4*)&axw[rb]        = hi;
        *(ushort4*)&axw[rb + 1024] = lo;
    }
}

// ---- batched bf16 MFMA NT-GEMM: O[m,n] = sum_k A[m,k]*B[n,k], 128x128 tile ----
#define TMt 128
#define TNt 128
#define TKt 32
#define PK 40   // padded LDS row stride (bf16): 80B -> only 2-way conflicts (free)

enum { FE_F32 = 0, FE_B16 = 1, FE_SIGB = 2, FE_TANHCAT = 3, FE_W = 4, FE_AK = 5, FE_VBLEND = 6 };

struct GemmJob {
    const u16* A; const u16* B; float* Of; u16* Ob;
    const float* bias; const float* extra; int K; int epi;
};
struct GemmBatch { GemmJob j[7]; };

__global__ __launch_bounds__(256)
void mfma_batch(GemmBatch batch)
{
    __shared__ u16 As[TMt * PK];
    __shared__ u16 Bs[TNt * PK];
    const GemmJob job = batch.j[blockIdx.x >> 8];
    const int tile = blockIdx.x & 255;
    const int m0 = (tile >> 3) << 7;
    const int n0 = (tile & 7) << 7;
    const int K  = job.K;
    const u16* __restrict__ A = job.A;
    const u16* __restrict__ B = job.B;

    const int t  = threadIdx.x;
    const int wv = t >> 6, ln = t & 63;
    const int wr = (wv >> 1) * 64;
    const int wc = (wv & 1) * 64;
    const int fr = ln & 15;
    const int fq = ln >> 4;
    const int srow = t >> 2;
    const int sk   = (t & 3) << 3;

    f32x4 acc[4][4];
#pragma unroll
    for (int i = 0; i < 4; ++i)
#pragma unroll
        for (int j = 0; j < 4; ++j) {
            acc[i][j][0] = 0.f; acc[i][j][1] = 0.f; acc[i][j][2] = 0.f; acc[i][j][3] = 0.f;
        }

    uint4 sa0 = *(const uint4*)&A[(size_t)(m0 + srow) * K + sk];
    uint4 sa1 = *(const uint4*)&A[(size_t)(m0 + srow + 64) * K + sk];
    uint4 sb0 = *(const uint4*)&B[(size_t)(n0 + srow) * K + sk];
    uint4 sb1 = *(const uint4*)&B[(size_t)(n0 + srow + 64) * K + sk];

    for (int k0 = 0; k0 < K; k0 += TKt) {
        __syncthreads();
        *(uint4*)&As[srow * PK + sk]        = sa0;
        *(uint4*)&As[(srow + 64) * PK + sk] = sa1;
        *(uint4*)&Bs[srow * PK + sk]        = sb0;
        *(uint4*)&Bs[(srow + 64) * PK + sk] = sb1;
        __syncthreads();
        if (k0 + TKt < K) {
            const int kn = k0 + TKt;
            sa0 = *(const uint4*)&A[(size_t)(m0 + srow) * K + kn + sk];
            sa1 = *(const uint4*)&A[(size_t)(m0 + srow + 64) * K + kn + sk];
            sb0 = *(const uint4*)&B[(size_t)(n0 + srow) * K + kn + sk];
            sb1 = *(const uint4*)&B[(size_t)(n0 + srow + 64) * K + kn + sk];
        }
        short8 af[4], bfr[4];
#pragma unroll
        for (int i = 0; i < 4; ++i) {
            af[i]  = *(const short8*)&As[(wr + i * 16 + fr) * PK + fq * 8];
            bfr[i] = *(const short8*)&Bs[(wc + i * 16 + fr) * PK + fq * 8];
        }
#pragma unroll
        for (int i = 0; i < 4; ++i)
#pragma unroll
            for (int j = 0; j < 4; ++j)
                acc[i][j] = __builtin_amdgcn_mfma_f32_16x16x32_bf16(af[i], bfr[j], acc[i][j], 0, 0, 0);
    }

    float* __restrict__ Of = job.Of;
    u16*   __restrict__ Ob = job.Ob;
    const float* bias  = job.bias;
    const float* extra = job.extra;
    const int epi = job.epi;

#pragma unroll
    for (int i = 0; i < 4; ++i) {
#pragma unroll
        for (int r = 0; r < 4; ++r) {
            const int m = m0 + wr + i * 16 + fq * 4 + r;
            const size_t rowf = (size_t)m * NDIM;
#pragma unroll
            for (int j = 0; j < 4; ++j) {
                const int n = n0 + wc + j * 16 + fr;
                const float val = acc[i][j][r];
                switch (epi) {
                case FE_F32:
                    Of[rowf + n] = val; break;
                case FE_B16:
                    Ob[rowf + n] = f2b(val); break;
                case FE_SIGB:
                    Ob[rowf + n] = f2b(sigf(val)); break;
                case FE_TANHCAT: {
                    const float tv = tanhf(val);
                    const u16 hi = f2b(tv);
                    const u16 lo = f2b(tv - b2f(hi));
                    const size_t rc = (size_t)m * 2048;
                    Ob[rc + n] = hi; Ob[rc + 1024 + n] = lo;
                    break; }
                case FE_W:
                    Of[rowf + n] = expf(-0.606531f * sigf(bias[n] + val)); break;
                case FE_AK: {
                    const float kv = Of[rowf + n];
                    Of[rowf + n] = kv * (1.f + (sigf(bias[n] + val) - 1.f) * extra[n]);
                    break; }
                default: { // FE_VBLEND
                    const float vv = Of[rowf + n];
                    const float s  = sigf(bias[n] + val);
                    Of[rowf + n] = vv + (extra[rowf + n] - vv) * s;
                    break; }
                }
            }
        }
    }
}

// ---- WKV7 chunked scan ----------------------------------------------------
// Exact linear decomposition: S_t = S_t(zero-start) + A_t (*) S_chunk_start,
// y_t = y_t(zero-start) + A_t (*) (S_chunk_start . r_t).
#define CL 128   // chunk length
#define NC 16    // chunks (T / CL)

// pass1: zero-start scan per (b,h,chunk,i-split). grid = B*H*NC*4, 64 thr.
// writes: y (zero-start), Acum (inclusive per-step decay prod), E (end states)
__global__ __launch_bounds__(64)
void wkv7_pass1(const float* __restrict__ r, const float* __restrict__ w,
                const float* __restrict__ k, const float* __restrict__ v,
                float* __restrict__ y, float* __restrict__ Acum,
                float* __restrict__ E, int Bn, int Tn, int Hn)
{
    const int blk = blockIdx.x;            // ((b*H+h)*NC + c)*4 + is
    const int is  = blk & 3;
    const int c   = (blk >> 2) & (NC - 1);
    const int bh  = blk >> 6;
    const int h   = bh % Hn;
    const int b   = bh / Hn;
    const int ln  = threadIdx.x;
    const int il  = ln >> 2;               // 0..15
    const int jq  = ln & 3;                // j-quad-of-16
    const int i   = is * 16 + il;
    const int C   = Hn * 64;
    const size_t base = (size_t)b * Tn * C + h * 64;
    const int t0 = c * CL;

    float st[16];
#pragma unroll
    for (int j = 0; j < 16; ++j) st[j] = 0.f;
    float cum = 1.f;

    size_t off = base + (size_t)t0 * C;
    float4 v4[4], r4[4];
    float wi, ki;
#pragma unroll
    for (int q = 0; q < 4; ++q) {
        v4[q] = *(const float4*)&v[off + jq * 16 + q * 4];
        r4[q] = *(const float4*)&r[off + jq * 16 + q * 4];
    }
    wi = w[off + i]; ki = k[off + i];

    for (int t = 0; t < CL; ++t) {
        const size_t noff = (t + 1 < CL) ? off + C : off;
        float4 nv[4], nr[4];
#pragma unroll
        for (int q = 0; q < 4; ++q) {
            nv[q] = *(const float4*)&v[noff + jq * 16 + q * 4];
            nr[q] = *(const float4*)&r[noff + jq * 16 + q * 4];
        }
        const float nw = w[noff + i], nk = k[noff + i];

        cum *= wi;
        float yi = 0.f;
#pragma unroll
        for (int q = 0; q < 4; ++q) {
            st[q * 4 + 0] = st[q * 4 + 0] * wi + ki * v4[q].x; yi += st[q * 4 + 0] * r4[q].x;
            st[q * 4 + 1] = st[q * 4 + 1] * wi + ki * v4[q].y; yi += st[q * 4 + 1] * r4[q].y;
            st[q * 4 + 2] = st[q * 4 + 2] * wi + ki * v4[q].z; yi += st[q * 4 + 2] * r4[q].z;
            st[q * 4 + 3] = st[q * 4 + 3] * wi + ki * v4[q].w; yi += st[q * 4 + 3] * r4[q].w;
        }
        yi += __shfl_xor(yi, 1);
        yi += __shfl_xor(yi, 2);
        if (jq == 0) {
            y[off + i]    = yi;
            Acum[off + i] = cum;
        }
#pragma unroll
        for (int q = 0; q < 4; ++q) { v4[q] = nv[q]; r4[q] = nr[q]; }
        wi = nw; ki = nk; off = noff;
    }

    const size_t eb = ((size_t)bh * NC + c) * 4096 + (size_t)i * 64 + jq * 16;
#pragma unroll
    for (int q = 0; q < 4; ++q)
        *(float4*)&E[eb + q * 4] = make_float4(st[q * 4 + 0], st[q * 4 + 1],
                                               st[q * 4 + 2], st[q * 4 + 3]);
}

// pass2: boundary states. grid = B*H, 256 thr; thread owns (i, 16 j's).
__global__ __launch_bounds__(256)
void wkv7_pass2(const float* __restrict__ E, const float* __restrict__ Acum,
                float* __restrict__ S0, int Bn, int Tn, int Hn)
{
    const int bh = blockIdx.x;
    const int h  = bh % Hn, b = bh / Hn;
    const int tid = threadIdx.x;
    const int i  = tid >> 2;
    const int jq = tid & 3;
    const int C  = Hn * 64;
    const size_t base = (size_t)bh * NC * 4096 + (size_t)i * 64 + jq * 16;

    float S[16];
#pragma unroll
    for (int q = 0; q < 16; ++q) S[q] = 0.f;

    for (int c = 0; c < NC; ++c) {
        const size_t idx = base + (size_t)c * 4096;
#pragma unroll
        for (int q = 0; q < 4; ++q)
            *(float4*)&S0[idx + q * 4] = make_float4(S[q * 4 + 0], S[q * 4 + 1],
                                                     S[q * 4 + 2], S[q * 4 + 3]);
        if (c + 1 < NC) {
            const float D = Acum[((size_t)b * Tn + c * CL + CL - 1) * C + h * 64 + i];
#pragma unroll
            for (int q = 0; q < 4; ++q) {
                const float4 e = *(const float4*)&E[idx + q * 4];
                S[q * 4 + 0] = D * S[q * 4 + 0] + e.x;
                S[q * 4 + 1] = D * S[q * 4 + 1] + e.y;
                S[q * 4 + 2] = D * S[q * 4 + 2] + e.z;
                S[q * 4 + 3] = D * S[q * 4 + 3] + e.w;
            }
        }
    }
}

// pass3: ycorr[t,i] = Acum[t,i] * sum_j S0[i,j] r_t[j]. grid = B*H*NC, 256 thr.
__global__ __launch_bounds__(256)
void wkv7_pass3(const float* __restrict__ r, const float* __restrict__ Acum,
                const float* __restrict__ S0, float* __restrict__ ycorr,
                int Bn, int Tn, int Hn)
{
    const int blk = blockIdx.x;
    const int c  = blk & (NC - 1);
    const int bh = blk >> 4;
    const int h  = bh % Hn, b = bh / Hn;
    const int tid = threadIdx.x;
    const int i  = tid >> 2;
    const int jq = tid & 3;
    const int C  = Hn * 64;

    const size_t sb = ((size_t)bh * NC + c) * 4096 + (size_t)i * 64 + jq * 16;
    float4 s0[4];
#pragma unroll
    for (int q = 0; q < 4; ++q) s0[q] = *(const float4*)&S0[sb + q * 4];

    size_t off = ((size_t)b * Tn + c * CL) * C + h * 64;
    for (int t = 0; t < CL; ++t) {
        float p = 0.f;
#pragma unroll
        for (int q = 0; q < 4; ++q) {
            const float4 r4 = *(const float4*)&r[off + jq * 16 + q * 4];
            p += s0[q].x * r4.x + s0[q].y * r4.y + s0[q].z * r4.z + s0[q].w * r4.w;
        }
        p += __shfl_xor(p, 1);
        p += __shfl_xor(p, 2);
        if (jq == 0) ycorr[off + i] = Acum[off + i] * p;
        off += C;
    }
}

// ---- fused LN + rkv + gate (y = y0 + ycorr), bf16 out ----
__global__ __launch_bounds__(256)
void ln_rkv_gate2(const float* __restrict__ y0, const float* __restrict__ yc,
                  const float* __restrict__ r, const float* __restrict__ k,
                  const float* __restrict__ v, const float* __restrict__ g,
                  const float* __restrict__ r_k, const float* __restrict__ lng,
                  const float* __restrict__ lnb, u16* __restrict__ z, int C)
{
    const int m   = blockIdx.x;
    const int tid = threadIdx.x;
    const size_t base = (size_t)m * C;
    const int c = tid << 2;

    const float4 a  = *(const float4*)&y0[base + c];
    const float4 b4 = *(const float4*)&yc[base + c];
    float4 y4;
    y4.x = a.x + b4.x; y4.y = a.y + b4.y; y4.z = a.z + b4.z; y4.w = a.w + b4.w;

    float s  = y4.x + y4.y + y4.z + y4.w;
    float ss = y4.x * y4.x + y4.y * y4.y + y4.z * y4.z + y4.w * y4.w;
#pragma unroll
    for (int o = 1; o < 64; o <<= 1) { s += __shfl_xor(s, o); ss += __shfl_xor(ss, o); }
    __shared__ float red[2][4];
    const int wid = tid >> 6, lid = tid & 63;
    if (lid == 0) { red[0][wid] = s; red[1][wid] = ss; }
    __syncthreads();
    s  = red[0][0] + red[0][1] + red[0][2] + red[0][3];
    ss = red[1][0] + red[1][1] + red[1][2] + red[1][3];
    const float mean = s / (float)C;
    const float var  = ss / (float)C - mean * mean;
    const float inv  = rsqrtf(var + 1e-5f);

    const float4 r4  = *(const float4*)&r[base + c];
    const float4 k4  = *(const float4*)&k[base + c];
    const float4 rk4 = *(const float4*)&r_k[c];
    float p = r4.x * k4.x * rk4.x + r4.y * k4.y * rk4.y + r4.z * k4.z * rk4.z + r4.w * k4.w * rk4.w;
    p += __shfl_xor(p, 1); p += __shfl_xor(p, 2); p += __shfl_xor(p, 4); p += __shfl_xor(p, 8);

    const float4 v4 = *(const float4*)&v[base + c];
    const float4 g4 = *(const float4*)&g[base + c];
    const float4 lg = *(const float4*)&lng[c];
    const float4 lb = *(const float4*)&lnb[c];
    ushort4 res;
    res.x = f2b(((y4.x - mean) * inv * lg.x + lb.x + p * v4.x) * g4.x);
    res.y = f2b(((y4.y - mean) * inv * lg.y + lb.y + p * v4.y) * g4.y);
    res.z = f2b(((y4.z - mean) * inv * lg.z + lb.z + p * v4.z) * g4.z);
    res.w = f2b(((y4.w - mean) * inv * lg.w + lb.w + p * v4.w) * g4.w);
    *(ushort4*)&z[base + c] = res;
}

// ============================ FALLBACK (round-1 fp32) =======================

#define BM 64
#define BN 64
#define BK 32
enum { A_PLAIN = 0, A_MIX = 1 };
enum { EP_STORE = 0, EP_TANH = 1, EP_W = 2, EP_SIGMOID = 3, EP_AK = 4, EP_VBLEND = 5 };

template<int AMODE, int EPI>
__global__ __launch_bounds__(256)
void gemm_nt(const float* __restrict__ A, const float* __restrict__ tm,
             const float* __restrict__ W, float* __restrict__ O,
             const float* __restrict__ bias, const float* __restrict__ extra,
             int M, int K, int N, int Tdim)
{
    __shared__ float As[BK][BM + 4];
    __shared__ float Bs[BK][BN + 4];
    const int tid  = threadIdx.x;
    const int m0   = blockIdx.y * BM;
    const int n0   = blockIdx.x * BN;
    const int lrow = tid >> 3;
    const int lcol = (tid & 7) << 2;
    const int ty   = tid >> 4;
    const int tx   = tid & 15;
    float acc[4][4] = {{0.f}};

    for (int k0 = 0; k0 < K; k0 += BK) {
#pragma unroll
        for (int rr = 0; rr < 2; ++rr) {
            const int row = lrow + rr * 32;
            const int m   = m0 + row;
            float4 av;
            if (AMODE == A_MIX) {
                const float4 xc = *(const float4*)&A[(size_t)m * K + k0 + lcol];
                float4 xp = make_float4(0.f, 0.f, 0.f, 0.f);
                if ((m % Tdim) != 0)
                    xp = *(const float4*)&A[(size_t)(m - 1) * K + k0 + lcol];
                const float4 tc = *(const float4*)&tm[k0 + lcol];
                av.x = xc.x + (xp.x - xc.x) * tc.x;
                av.y = xc.y + (xp.y - xc.y) * tc.y;
                av.z = xc.z + (xp.z - xc.z) * tc.z;
                av.w = xc.w + (xp.w - xc.w) * tc.w;
            } else {
                av = *(const float4*)&A[(size_t)m * K + k0 + lcol];
            }
            As[lcol + 0][row] = av.x; As[lcol + 1][row] = av.y;
            As[lcol + 2][row] = av.z; As[lcol + 3][row] = av.w;
            const float4 bv = *(const float4*)&W[(size_t)(n0 + row) * K + k0 + lcol];
            Bs[lcol + 0][row] = bv.x; Bs[lcol + 1][row] = bv.y;
            Bs[lcol + 2][row] = bv.z; Bs[lcol + 3][row] = bv.w;
        }
        __syncthreads();
#pragma unroll
        for (int kk = 0; kk < BK; ++kk) {
            const float4 a4 = *(const float4*)&As[kk][ty << 2];
            const float4 b4 = *(const float4*)&Bs[kk][tx << 2];
            acc[0][0] += a4.x * b4.x; acc[0][1] += a4.x * b4.y; acc[0][2] += a4.x * b4.z; acc[0][3] += a4.x * b4.w;
            acc[1][0] += a4.y * b4.x; acc[1][1] += a4.y * b4.y; acc[1][2] += a4.y * b4.z; acc[1][3] += a4.y * b4.w;
            acc[2][0] += a4.z * b4.x; acc[2][1] += a4.z * b4.y; acc[2][2] += a4.z * b4.z; acc[2][3] += a4.z * b4.w;
            acc[3][0] += a4.w * b4.x; acc[3][1] += a4.w * b4.y; acc[3][2] += a4.w * b4.z; acc[3][3] += a4.w * b4.w;
        }
        __syncthreads();
    }

#pragma unroll
    for (int ii = 0; ii < 4; ++ii) {
        const int m = m0 + (ty << 2) + ii;
        const int n = n0 + (tx << 2);
        const size_t o = (size_t)m * N + n;
        const float a0v = acc[ii][0], a1v = acc[ii][1], a2v = acc[ii][2], a3v = acc[ii][3];
        float4 res;
        if (EPI == EP_STORE) {
            res = make_float4(a0v, a1v, a2v, a3v);
        } else if (EPI == EP_TANH) {
            res = make_float4(tanhf(a0v), tanhf(a1v), tanhf(a2v), tanhf(a3v));
        } else if (EPI == EP_SIGMOID) {
            res = make_float4(sigf(a0v), sigf(a1v), sigf(a2v), sigf(a3v));
        } else if (EPI == EP_W) {
            const float4 b = *(const float4*)&bias[n];
            res.x = expf(-0.606531f * sigf(b.x + a0v));
            res.y = expf(-0.606531f * sigf(b.y + a1v));
            res.z = expf(-0.606531f * sigf(b.z + a2v));
            res.w = expf(-0.606531f * sigf(b.w + a3v));
        } else if (EPI == EP_AK) {
            const float4 b  = *(const float4*)&bias[n];
            const float4 ka = *(const float4*)&extra[n];
            const float4 kv = *(const float4*)&O[o];
            res.x = kv.x * (1.f + (sigf(b.x + a0v) - 1.f) * ka.x);
            res.y = kv.y * (1.f + (sigf(b.y + a1v) - 1.f) * ka.y);
            res.z = kv.z * (1.f + (sigf(b.z + a2v) - 1.f) * ka.z);
            res.w = kv.w * (1.f + (sigf(b.w + a3v) - 1.f) * ka.w);
        } else {
            const float4 b  = *(const float4*)&bias[n];
            const float4 vf = *(const float4*)&extra[o];
            const float4 vv = *(const float4*)&O[o];
            float sx;
            sx = sigf(b.x + a0v); res.x = vv.x + (vf.x - vv.x) * sx;
            sx = sigf(b.y + a1v); res.y = vv.y + (vf.y - vv.y) * sx;
            sx = sigf(b.z + a2v); res.z = vv.z + (vf.z - vv.z) * sx;
            sx = sigf(b.w + a3v); res.w = vv.w + (vf.w - vv.w) * sx;
        }
        *(float4*)&O[o] = res;
    }
}

__global__ __launch_bounds__(64)
void wkv7_scan(const float* __restrict__ r, const float* __restrict__ w,
               const float* __restrict__ k, const float* __restrict__ v,
               float* __restrict__ y, int Bn, int Tn, int Hn)
{
    const int blk  = blockIdx.x;
    const int s    = blk & 3;
    const int h    = (blk >> 2) % Hn;
    const int b    = blk / (4 * Hn);
    const int lane = threadIdx.x;
    const int il   = lane >> 2;
    const int q    = lane & 3;
    const int i    = s * 16 + il;
    const int C    = Hn * 64;
    const size_t base = (size_t)b * Tn * C + h * 64;

    float st[16];
#pragma unroll
    for (int j = 0; j < 16; ++j) st[j] = 0.f;

    __shared__ float vs[4][64];
    __shared__ float rs[4][64];

    for (int t0 = 0; t0 < Tn; t0 += 4) {
        float vl[4], rl[4], wl[4], kl[4];
#pragma unroll
        for (int u = 0; u < 4; ++u) {
            const size_t off = base + (size_t)(t0 + u) * C;
            vl[u] = v[off + lane]; rl[u] = r[off + lane];
            wl[u] = w[off + i];    kl[u] = k[off + i];
        }
        __syncthreads();
#pragma unroll
        for (int u = 0; u < 4; ++u) { vs[u][lane] = vl[u]; rs[u][lane] = rl[u]; }
        __syncthreads();
#pragma unroll
        for (int u = 0; u < 4; ++u) {
            const float wi = wl[u], ki = kl[u];
            float yi = 0.f;
#pragma unroll
            for (int jg = 0; jg < 4; ++jg) {
                const float4 v4 = *(const float4*)&vs[u][q * 16 + jg * 4];
                const float4 r4 = *(const float4*)&rs[u][q * 16 + jg * 4];
                const int j = jg * 4;
                st[j + 0] = st[j + 0] * wi + ki * v4.x; yi += st[j + 0] * r4.x;
                st[j + 1] = st[j + 1] * wi + ki * v4.y; yi += st[j + 1] * r4.y;
                st[j + 2] = st[j + 2] * wi + ki * v4.z; yi += st[j + 2] * r4.z;
                st[j + 3] = st[j + 3] * wi + ki * v4.w; yi += st[j + 3] * r4.w;
            }
            yi += __shfl_xor(yi, 1);
            yi += __shfl_xor(yi, 2);
            if (q == 0) y[base + (size_t)(t0 + u) * C + i] = yi;
        }
    }
}

__global__ __launch_bounds__(256)
void ln_rkv_gate(const float* __restrict__ y, const float* __restrict__ r,
                 const float* __restrict__ k, const float* __restrict__ v,
                 const float* __restrict__ g, const float* __restrict__ r_k,
                 const float* __restrict__ lng, const float* __restrict__ lnb,
                 float* __restrict__ z, int C)
{
    const int m   = blockIdx.x;
    const int tid = threadIdx.x;
    const size_t base = (size_t)m * C;
    const int c = tid << 2;

    const float4 y4 = *(const float4*)&y[base + c];
    float s  = y4.x + y4.y + y4.z + y4.w;
    float ss = y4.x * y4.x + y4.y * y4.y + y4.z * y4.z + y4.w * y4.w;
#pragma unroll
    for (int o = 1; o < 64; o <<= 1) { s += __shfl_xor(s, o); ss += __shfl_xor(ss, o); }
    __shared__ float red[2][4];
    const int wid = tid >> 6, lid = tid & 63;
    if (lid == 0) { red[0][wid] = s; red[1][wid] = ss; }
    __syncthreads();
    s  = red[0][0] + red[0][1] + red[0][2] + red[0][3];
    ss = red[1][0] + red[1][1] + red[1][2] + red[1][3];
    const float mean = s / (float)C;
    const float var  = ss / (float)C - mean * mean;
    const float inv  = rsqrtf(var + 1e-5f);

    const float4 r4  = *(const float4*)&r[base + c];
    const float4 k4  = *(const float4*)&k[base + c];
    const float4 rk4 = *(const float4*)&r_k[c];
    float p = r4.x * k4.x * rk4.x + r4.y * k4.y * rk4.y + r4.z * k4.z * rk4.z + r4.w * k4.w * rk4.w;
    p += __shfl_xor(p, 1); p += __shfl_xor(p, 2); p += __shfl_xor(p, 4); p += __shfl_xor(p, 8);

    const float4 v4 = *(const float4*)&v[base + c];
    const float4 g4 = *(const float4*)&g[base + c];
    const float4 lg = *(const float4*)&lng[c];
    const float4 lb = *(const float4*)&lnb[c];
    float4 res;
    res.x = ((y4.x - mean) * inv * lg.x + lb.x + p * v4.x) * g4.x;
    res.y = ((y4.y - mean) * inv * lg.y + lb.y + p * v4.y) * g4.y;
    res.z = ((y4.z - mean) * inv * lg.z + lb.z + p * v4.z) * g4.z;
    res.w = ((y4.w - mean) * inv * lg.w + lb.w + p * v4.w) * g4.w;
    *(float4*)&z[base + c] = res;
}

// ============================ LAUNCH ========================================

extern "C" void kernel_launch(void* const* d_in, const int* in_sizes, int n_in,
                              void* d_out, int out_size, void* d_ws, size_t ws_size,
                              hipStream_t stream)
{
    const float* x    = (const float*)d_in[0];
    const float* vfst = (const float*)d_in[1];
    const float* Wr   = (const float*)d_in[2];
    const float* Wk   = (const float*)d_in[3];
    const float* Wv   = (const float*)d_in[4];
    const float* Wo   = (const float*)d_in[5];
    const float* Wg1  = (const float*)d_in[6];
    const float* Wg2  = (const float*)d_in[7];
    const float* W1   = (const float*)d_in[8];
    const float* W2   = (const float*)d_in[9];
    const float* A1   = (const float*)d_in[10];
    const float* A2   = (const float*)d_in[11];
    const float* V1   = (const float*)d_in[12];
    const float* V2   = (const float*)d_in[13];
    const float* tm_r = (const float*)d_in[14];
    const float* tm_w = (const float*)d_in[15];
    const float* tm_k = (const float*)d_in[16];
    const float* tm_v = (const float*)d_in[17];
    const float* tm_a = (const float*)d_in[18];
    const float* tm_g = (const float*)d_in[19];
    const float* w0   = (const float*)d_in[20];
    const float* a0   = (const float*)d_in[21];
    const float* v0   = (const float*)d_in[22];
    const float* k_a  = (const float*)d_in[24];
    const float* r_k  = (const float*)d_in[25];
    const float* ln_g = (const float*)d_in[26];
    const float* ln_b = (const float*)d_in[27];
    float* out = (float*)d_out;

    const int Bn = 2, Tn = 2048, C = 1024, Hh = 16;
    const int M = Bn * Tn, K = C, N = C;
    const size_t MBy = (size_t)1 << 20;
    const size_t NEED = 204 * MBy;

    if (ws_size >= NEED) {
        unsigned char* w8 = (unsigned char*)d_ws;
        u16* wb    = (u16*)(w8 + 0);            // 10 x 2MB bf16 weights
        u16* w1cat = (u16*)(w8 + 20 * MBy);     // 4MB [hi|hi]
        u16* w2cat = (u16*)(w8 + 24 * MBy);     // 4MB [hi|hi]
        u16* axr   = (u16*)(w8 + 28 * MBy);
        u16* axk   = (u16*)(w8 + 36 * MBy);
        u16* axv   = (u16*)(w8 + 44 * MBy);
        u16* axa   = (u16*)(w8 + 52 * MBy);
        u16* axg   = (u16*)(w8 + 60 * MBy);
        u16* axw   = (u16*)(w8 + 68 * MBy);     // 16MB [hi|lo]
        u16* btw   = (u16*)(w8 + 84 * MBy);     // 16MB [hi|lo]
        u16* bt1a  = (u16*)(w8 + 100 * MBy);
        u16* bt1g  = (u16*)(w8 + 108 * MBy);
        u16* bt1v  = (u16*)(w8 + 116 * MBy);
        float* br  = (float*)(w8 + 124 * MBy);
        float* bk  = (float*)(w8 + 140 * MBy);
        float* bv  = (float*)(w8 + 156 * MBy);
        float* bw  = (float*)(w8 + 172 * MBy);
        float* bg  = (float*)(w8 + 188 * MBy);
        // scan-phase aliases (regions dead after GEMM stage 2)
        float* by  = (float*)(w8 + 28 * MBy);   // y zero-start, 16MB
        float* byc = (float*)(w8 + 44 * MBy);   // ycorr, 16MB
        float* bA  = (float*)(w8 + 60 * MBy);   // Acum, 16MB
        float* bE  = (float*)(w8 + 76 * MBy);   // end states, 8MB
        float* bS0 = (float*)(w8 + 84 * MBy);   // boundary states, 8MB
        u16*  bz   = (u16*)(w8 + 100 * MBy);    // LN output, 8MB

        u16* wWr  = wb;              u16* wWk  = wb + (1u << 20);
        u16* wWv  = wb + (2u << 20); u16* wWo  = wb + (3u << 20);
        u16* wWg1 = wb + (4u << 20); u16* wWg2 = wb + (5u << 20);
        u16* wA1  = wb + (6u << 20); u16* wA2  = wb + (7u << 20);
        u16* wV1  = wb + (8u << 20); u16* wV2  = wb + (9u << 20);

        P10 p10;
        p10.p[0] = Wr;  p10.p[1] = Wk;  p10.p[2] = Wv;  p10.p[3] = Wo;
        p10.p[4] = Wg1; p10.p[5] = Wg2; p10.p[6] = A1;  p10.p[7] = A2;
        p10.p[8] = V1;  p10.p[9] = V2;

        conv_w10<<<dim3(10240), dim3(256), 0, stream>>>(p10, wb);
        conv_cat2<<<dim3(1024), dim3(256), 0, stream>>>(W1, W2, w1cat, w2cat);
        prep_act<<<dim3(4096), dim3(256), 0, stream>>>(x, tm_r, tm_w, tm_k, tm_v, tm_a, tm_g,
                                                       axr, axk, axv, axa, axg, axw, Tn);

        // stage 1: 7 independent GEMMs (K=2048 job first for tail balance)
        GemmBatch s1;
        s1.j[0] = { axw, w1cat, nullptr, btw,  nullptr, nullptr, 2048, FE_TANHCAT };
        s1.j[1] = { axr, wWr,   br,      nullptr, nullptr, nullptr, 1024, FE_F32 };
        s1.j[2] = { axk, wWk,   bk,      nullptr, nullptr, nullptr, 1024, FE_F32 };
        s1.j[3] = { axv, wWv,   bv,      nullptr, nullptr, nullptr, 1024, FE_F32 };
        s1.j[4] = { axa, wA1,   nullptr, bt1a, nullptr, nullptr, 1024, FE_B16 };
        s1.j[5] = { axg, wWg1,  nullptr, bt1g, nullptr, nullptr, 1024, FE_SIGB };
        s1.j[6] = { axv, wV1,   nullptr, bt1v, nullptr, nullptr, 1024, FE_B16 };
        mfma_batch<<<dim3(7 * 256), dim3(256), 0, stream>>>(s1);

        // stage 2: 4 dependent GEMMs
        GemmBatch s2;
        s2.j[0] = { btw,  w2cat, bw, nullptr, w0, nullptr, 2048, FE_W };
        s2.j[1] = { bt1a, wA2,   bk, nullptr, a0, k_a,     1024, FE_AK };
        s2.j[2] = { bt1g, wWg2,  bg, nullptr, nullptr, nullptr, 1024, FE_F32 };
        s2.j[3] = { bt1v, wV2,   bv, nullptr, v0, vfst,    1024, FE_VBLEND };
        s2.j[4] = s2.j[0]; s2.j[5] = s2.j[0]; s2.j[6] = s2.j[0];
        mfma_batch<<<dim3(4 * 256), dim3(256), 0, stream>>>(s2);

        // chunked scan
        wkv7_pass1<<<dim3(Bn * Hh * NC * 4), dim3(64), 0, stream>>>(br, bw, bk, bv,
                                                                    by, bA, bE, Bn, Tn, Hh);
        wkv7_pass2<<<dim3(Bn * Hh), dim3(256), 0, stream>>>(bE, bA, bS0, Bn, Tn, Hh);
        wkv7_pass3<<<dim3(Bn * Hh * NC), dim3(256), 0, stream>>>(br, bA, bS0, byc, Bn, Tn, Hh);

        // LN + rkv + gate -> bz (bf16)
        ln_rkv_gate2<<<dim3(M), dim3(256), 0, stream>>>(by, byc, br, bk, bv, bg,
                                                        r_k, ln_g, ln_b, bz, C);
        // out = z @ Wo^T
        GemmBatch s3;
        s3.j[0] = { bz, wWo, out, nullptr, nullptr, nullptr, 1024, FE_F32 };
        s3.j[1] = s3.j[0]; s3.j[2] = s3.j[0]; s3.j[3] = s3.j[0];
        s3.j[4] = s3.j[0]; s3.j[5] = s3.j[0]; s3.j[6] = s3.j[0];
        mfma_batch<<<dim3(256), dim3(256), 0, stream>>>(s3);
        return;
    }

    // -------- fallback: round-1 fp32 path (96MB ws) --------
    const size_t S = (size_t)M * C;
    float* ws = (float*)d_ws;
    float* br = ws;
    float* bk = ws + S;
    float* bv = ws + 2 * S;
    float* bw = ws + 3 * S;
    float* bg = ws + 4 * S;
    float* bt = ws + 5 * S;
    float* by = bt;

    dim3 grid(N / BN, M / BM);
    dim3 blk(256);

    gemm_nt<A_MIX, EP_STORE><<<grid, blk, 0, stream>>>(x, tm_r, Wr, br, nullptr, nullptr, M, K, N, Tn);
    gemm_nt<A_MIX, EP_STORE><<<grid, blk, 0, stream>>>(x, tm_k, Wk, bk, nullptr, nullptr, M, K, N, Tn);
    gemm_nt<A_MIX, EP_STORE><<<grid, blk, 0, stream>>>(x, tm_v, Wv, bv, nullptr, nullptr, M, K, N, Tn);
    gemm_nt<A_MIX, EP_TANH><<<grid, blk, 0, stream>>>(x, tm_w, W1, bt, nullptr, nullptr, M, K, N, Tn);
    gemm_nt<A_PLAIN, EP_W><<<grid, blk, 0, stream>>>(bt, nullptr, W2, bw, w0, nullptr, M, K, N, Tn);
    gemm_nt<A_MIX, EP_STORE><<<grid, blk, 0, stream>>>(x, tm_a, A1, bt, nullptr, nullptr, M, K, N, Tn);
    gemm_nt<A_PLAIN, EP_AK><<<grid, blk, 0, stream>>>(bt, nullptr, A2, bk, a0, k_a, M, K, N, Tn);
    gemm_nt<A_MIX, EP_SIGMOID><<<grid, blk, 0, stream>>>(x, tm_g, Wg1, bt, nullptr, nullptr, M, K, N, Tn);
    gemm_nt<A_PLAIN, EP_STORE><<<grid, blk, 0, stream>>>(bt, nullptr, Wg2, bg, nullptr, nullptr, M, K, N, Tn);
    gemm_nt<A_MIX, EP_STORE><<<grid, blk, 0, stream>>>(x, tm_v, V1, bt, nullptr, nullptr, M, K, N, Tn);
    gemm_nt<A_PLAIN, EP_VBLEND><<<grid, blk, 0, stream>>>(bt, nullptr, V2, bv, v0, vfst, M, K, N, Tn);
    wkv7_scan<<<dim3(Bn * Hh * 4), dim3(64), 0, stream>>>(br, bw, bk, bv, by, Bn, Tn, Hh);
    ln_rkv_gate<<<dim3(M), dim3(256), 0, stream>>>(by, br, bk, bv, bg, r_k, ln_g, ln_b, by, C);
    gemm_nt<A_PLAIN, EP_STORE><<<grid, blk, 0, stream>>>(by, nullptr, Wo, out, nullptr, nullptr, M, K, N, Tn);
}

// Round 4
// 631.599 us; speedup vs baseline: 3.8331x; 1.1323x over previous
//
#include <hip/hip_runtime.h>
#include <hip/hip_bf16.h>
#include <cmath>

// ---------------------------------------------------------------------------
// RWKV-7 TimeMixing. B=2, T=2048, C=1024, H=16, N=64, M=4096.
// FAST path (ws >= 172MB):
//   - bf16 MFMA GEMMs, global_load_lds + double-buffered LDS pipeline,
//     XCD m-grouped tile swizzle (blocks with same blockIdx%8 share A/B in L2)
//   - r/k/v/g stored bf16 (w fp32), w-path in bf16x2 split (K=2048)
//   - chunked WKV7 scan (exact linear-state decomposition, Acum recomputed)
//   - fused LN + rkv + gate -> bf16, final Wo GEMM
// FALLBACK: round-1 fp32 path, known-good.
// ---------------------------------------------------------------------------

typedef unsigned short u16;
typedef __attribute__((ext_vector_type(8))) short short8;   // 8 x bf16 frag
typedef __attribute__((ext_vector_type(4))) float f32x4;

#define NDIM 1024

__device__ __forceinline__ float sigf(float x) { return 1.f / (1.f + expf(-x)); }
__device__ __forceinline__ u16 f2b(float f) {
    union { float f; unsigned int u; } v; v.f = f;
    unsigned int r = (v.u + 0x7FFFu + ((v.u >> 16) & 1u)) >> 16;
    return (u16)r;
}
__device__ __forceinline__ float b2f(u16 b) {
    union { unsigned int u; float f; } v; v.u = ((unsigned int)b) << 16;
    return v.f;
}
__device__ __forceinline__ float4 b2f4(ushort4 u) {
    return make_float4(b2f(u.x), b2f(u.y), b2f(u.z), b2f(u.w));
}

#define GLD16(gp, lp)                                                         \
    __builtin_amdgcn_global_load_lds(                                         \
        (const __attribute__((address_space(1))) void*)(gp),                  \
        (__attribute__((address_space(3))) void*)(lp), 16, 0, 0)

// ============================ FAST PATH ====================================

// ---- prep: 10 plain weights fp32 -> bf16 ----
struct P10 { const float* p[10]; };
__global__ __launch_bounds__(256)
void conv_w10(P10 src, u16* __restrict__ dst) {
    const int wi = blockIdx.x >> 10;
    const int t  = (((blockIdx.x & 1023) << 8) | threadIdx.x) << 2;
    const float4 v = *(const float4*)&src.p[wi][t];
    ushort4 o; o.x = f2b(v.x); o.y = f2b(v.y); o.z = f2b(v.z); o.w = f2b(v.w);
    *(ushort4*)&dst[((size_t)wi << 20) + t] = o;
}

// ---- prep: W1,W2 -> [hi|hi] duplicated cat layout (N x 2C) ----
__global__ __launch_bounds__(256)
void conv_cat2(const float* __restrict__ W1, const float* __restrict__ W2,
               u16* __restrict__ c1, u16* __restrict__ c2) {
    const int t = (blockIdx.x * 256 + threadIdx.x) << 2;
    const int n = t >> 10, c = t & 1023;
    const size_t rb = (size_t)n * 2048 + c;
#pragma unroll
    for (int wsel = 0; wsel < 2; ++wsel) {
        const float* W = wsel ? W2 : W1;
        u16* dc = wsel ? c2 : c1;
        const float4 v = *(const float4*)&W[t];
        ushort4 hi;
        hi.x = f2b(v.x); hi.y = f2b(v.y); hi.z = f2b(v.z); hi.w = f2b(v.w);
        *(ushort4*)&dc[rb]        = hi;
        *(ushort4*)&dc[rb + 1024] = hi;
    }
}

// ---- prep: token-shift mixes -> bf16 activations (w-path [hi|lo] cat) ----
__global__ __launch_bounds__(256)
void prep_act(const float* __restrict__ x,
              const float* __restrict__ tmr, const float* __restrict__ tmw,
              const float* __restrict__ tmk, const float* __restrict__ tmv,
              const float* __restrict__ tma, const float* __restrict__ tmg,
              u16* __restrict__ axr, u16* __restrict__ axk, u16* __restrict__ axv,
              u16* __restrict__ axa, u16* __restrict__ axg, u16* __restrict__ axw,
              int T) {
    const int t = (blockIdx.x * 256 + threadIdx.x) << 2;
    const int m = t >> 10, c = t & 1023;
    const float4 xc = *(const float4*)&x[t];
    float4 xp = make_float4(0.f, 0.f, 0.f, 0.f);
    if ((m % T) != 0) xp = *(const float4*)&x[t - 1024];
    const float4 d = make_float4(xp.x - xc.x, xp.y - xc.y, xp.z - xc.z, xp.w - xc.w);
#define MIX_STORE(tm, dstp)                                            \
    {   const float4 tc = *(const float4*)&tm[c];                      \
        ushort4 o;                                                     \
        o.x = f2b(xc.x + d.x * tc.x); o.y = f2b(xc.y + d.y * tc.y);    \
        o.z = f2b(xc.z + d.z * tc.z); o.w = f2b(xc.w + d.w * tc.w);    \
        *(ushort4*)&dstp[t] = o; }
    MIX_STORE(tmr, axr) MIX_STORE(tmk, axk) MIX_STORE(tmv, axv)
    MIX_STORE(tma, axa) MIX_STORE(tmg, axg)
#undef MIX_STORE
    {   // w path: [hi | lo]
        const float4 tc = *(const float4*)&tmw[c];
        float4 v = make_float4(xc.x + d.x * tc.x, xc.y + d.y * tc.y,
                               xc.z + d.z * tc.z, xc.w + d.w * tc.w);
        ushort4 hi, lo;
        hi.x = f2b(v.x); lo.x = f2b(v.x - b2f(hi.x));
        hi.y = f2b(v.y); lo.y = f2b(v.y - b2f(hi.y));
        hi.z = f2b(v.z); lo.z = f2b(v.z - b2f(hi.z));
        hi.w = f2b(v.w); lo.w = f2b(v.w - b2f(hi.w));
        const size_t rb = (size_t)m * 2048 + c;
        *(ushort4*)&axw[rb]        = hi;
        *(ushort4*)&axw[rb + 1024] = lo;
    }
}

// ---- batched bf16 MFMA NT-GEMM, 128x128 tile, global_load_lds dbuf ----
#define TKt 32

enum { FE_F32 = 0, FE_B16 = 1, FE_SIGB = 2, FE_TANHCAT = 3, FE_W = 4, FE_AK = 5, FE_VBLEND = 6 };

struct GemmJob {
    const u16* A; const u16* B; float* Of; u16* Ob;
    const float* bias; const float* extra; int K; int epi;
};
struct GemmBatch { GemmJob j[7]; };

__global__ __launch_bounds__(256)
void mfma_batch(GemmBatch batch)
{
    // 2 x (A 128x32 + B 128x32) bf16, unpadded (b128 reads conflict-free)
    __shared__ u16 As[2][128 * 32];
    __shared__ u16 Bs[2][128 * 32];
    const GemmJob job = batch.j[blockIdx.x >> 8];
    const int bid = blockIdx.x & 255;
    // XCD m-grouping: xcd = bid&7 owns m-tiles 4x..4x+3 for all n-tiles.
    const int m0 = (((bid & 7) << 2) + ((bid >> 3) & 3)) << 7;
    const int n0 = (bid >> 5) << 7;
    const int K  = job.K;
    const u16* __restrict__ Ag = job.A;
    const u16* __restrict__ Bg = job.B;

    const int t  = threadIdx.x;
    const int wv = t >> 6, ln = t & 63;
    const int wr = (wv >> 1) * 64;      // wave m-offset in tile
    const int wc = (wv & 1) * 64;       // wave n-offset in tile
    const int fr = ln & 15;
    const int fq = ln >> 4;
    const int lrow = ln >> 2;           // 0..15 row within 16-row slab
    const int lcol = (ln & 3) << 3;     // 0,8,16,24 (u16)

    f32x4 acc[4][4];
#pragma unroll
    for (int i = 0; i < 4; ++i)
#pragma unroll
        for (int j = 0; j < 4; ++j) {
            acc[i][j][0] = 0.f; acc[i][j][1] = 0.f; acc[i][j][2] = 0.f; acc[i][j][3] = 0.f;
        }

    // per-wave slab bases: call c covers tile rows [c*64 + wv*16, +16)
    const int slab0 = (wv << 4);        // rows 0..63
    const int slab1 = 64 + (wv << 4);   // rows 64..127

    // issue loads of k-tile at column k0 into buffer buf
    auto issue = [&](int k0, int buf) {
        const size_t ga0 = (size_t)(m0 + slab0 + lrow) * K + k0 + lcol;
        const size_t ga1 = (size_t)(m0 + slab1 + lrow) * K + k0 + lcol;
        const size_t gb0 = (size_t)(n0 + slab0 + lrow) * K + k0 + lcol;
        const size_t gb1 = (size_t)(n0 + slab1 + lrow) * K + k0 + lcol;
        GLD16(Ag + ga0, &As[buf][slab0 * 32]);
        GLD16(Ag + ga1, &As[buf][slab1 * 32]);
        GLD16(Bg + gb0, &Bs[buf][slab0 * 32]);
        GLD16(Bg + gb1, &Bs[buf][slab1 * 32]);
    };

    issue(0, 0);
    const int NT = K / TKt;
    int cur = 0;
    for (int it = 0; it < NT; ++it) {
        __syncthreads();                 // drains vmcnt -> tile 'it' resident
        if (it + 1 < NT) issue((it + 1) * TKt, cur ^ 1);
        short8 af[4], bfr[4];
#pragma unroll
        for (int i = 0; i < 4; ++i) {
            af[i]  = *(const short8*)&As[cur][(wr + i * 16 + fr) * 32 + fq * 8];
            bfr[i] = *(const short8*)&Bs[cur][(wc + i * 16 + fr) * 32 + fq * 8];
        }
#pragma unroll
        for (int i = 0; i < 4; ++i)
#pragma unroll
            for (int j = 0; j < 4; ++j)
                acc[i][j] = __builtin_amdgcn_mfma_f32_16x16x32_bf16(af[i], bfr[j], acc[i][j], 0, 0, 0);
        cur ^= 1;
    }

    float* __restrict__ Of = job.Of;
    u16*   __restrict__ Ob = job.Ob;
    const float* bias  = job.bias;
    const float* extra = job.extra;
    const int epi = job.epi;

#pragma unroll
    for (int i = 0; i < 4; ++i) {
#pragma unroll
        for (int r = 0; r < 4; ++r) {
            const int m = m0 + wr + i * 16 + fq * 4 + r;
            const size_t rowf = (size_t)m * NDIM;
#pragma unroll
            for (int j = 0; j < 4; ++j) {
                const int n = n0 + wc + j * 16 + fr;
                const float val = acc[i][j][r];
                switch (epi) {
                case FE_F32:
                    Of[rowf + n] = val; break;
                case FE_B16:
                    Ob[rowf + n] = f2b(val); break;
                case FE_SIGB:
                    Ob[rowf + n] = f2b(sigf(val)); break;
                case FE_TANHCAT: {
                    const float tv = tanhf(val);
                    const u16 hi = f2b(tv);
                    const u16 lo = f2b(tv - b2f(hi));
                    const size_t rc = (size_t)m * 2048;
                    Ob[rc + n] = hi; Ob[rc + 1024 + n] = lo;
                    break; }
                case FE_W:
                    Of[rowf + n] = expf(-0.606531f * sigf(bias[n] + val)); break;
                case FE_AK: {
                    const float kv = b2f(Ob[rowf + n]);
                    Ob[rowf + n] = f2b(kv * (1.f + (sigf(bias[n] + val) - 1.f) * extra[n]));
                    break; }
                default: { // FE_VBLEND
                    const float vv = b2f(Ob[rowf + n]);
                    const float s  = sigf(bias[n] + val);
                    Ob[rowf + n] = f2b(vv + (extra[rowf + n] - vv) * s);
                    break; }
                }
            }
        }
    }
}

// ---- WKV7 chunked scan ----------------------------------------------------
#define CL 128
#define NC 16

// pass1: zero-start scan per (b,h,chunk,i-split). r/k/v bf16, w fp32.
__global__ __launch_bounds__(64)
void wkv7_pass1(const u16* __restrict__ r, const float* __restrict__ w,
                const u16* __restrict__ k, const u16* __restrict__ v,
                float* __restrict__ y, float* __restrict__ Dend,
                float* __restrict__ E, int Bn, int Tn, int Hn)
{
    const int blk = blockIdx.x;            // ((b*H+h)*NC + c)*4 + is
    const int is  = blk & 3;
    const int c   = (blk >> 2) & (NC - 1);
    const int bh  = blk >> 6;
    const int h   = bh % Hn;
    const int b   = bh / Hn;
    const int ln  = threadIdx.x;
    const int il  = ln >> 2;
    const int jq  = ln & 3;
    const int i   = is * 16 + il;
    const int C   = Hn * 64;
    const size_t base = (size_t)b * Tn * C + h * 64;

    float st[16];
#pragma unroll
    for (int j = 0; j < 16; ++j) st[j] = 0.f;
    float cum = 1.f;

    size_t off = base + (size_t)(c * CL) * C;
    ushort4 v4[4], r4[4];
    float wi; u16 ki;
#pragma unroll
    for (int q = 0; q < 4; ++q) {
        v4[q] = *(const ushort4*)&v[off + jq * 16 + q * 4];
        r4[q] = *(const ushort4*)&r[off + jq * 16 + q * 4];
    }
    wi = w[off + i]; ki = k[off + i];

    for (int t = 0; t < CL; ++t) {
        const size_t noff = (t + 1 < CL) ? off + C : off;
        ushort4 nv[4], nr[4];
#pragma unroll
        for (int q = 0; q < 4; ++q) {
            nv[q] = *(const ushort4*)&v[noff + jq * 16 + q * 4];
            nr[q] = *(const ushort4*)&r[noff + jq * 16 + q * 4];
        }
        const float nw = w[noff + i];
        const u16   nk = k[noff + i];

        cum *= wi;
        const float kf = b2f(ki);
        float yi = 0.f;
#pragma unroll
        for (int q = 0; q < 4; ++q) {
            const float4 vf = b2f4(v4[q]);
            const float4 rf = b2f4(r4[q]);
            st[q * 4 + 0] = st[q * 4 + 0] * wi + kf * vf.x; yi += st[q * 4 + 0] * rf.x;
            st[q * 4 + 1] = st[q * 4 + 1] * wi + kf * vf.y; yi += st[q * 4 + 1] * rf.y;
            st[q * 4 + 2] = st[q * 4 + 2] * wi + kf * vf.z; yi += st[q * 4 + 2] * rf.z;
            st[q * 4 + 3] = st[q * 4 + 3] * wi + kf * vf.w; yi += st[q * 4 + 3] * rf.w;
        }
        yi += __shfl_xor(yi, 1);
        yi += __shfl_xor(yi, 2);
        if (jq == 0) y[off + i] = yi;
#pragma unroll
        for (int q = 0; q < 4; ++q) { v4[q] = nv[q]; r4[q] = nr[q]; }
        wi = nw; ki = nk; off = noff;
    }

    if (jq == 0) Dend[((size_t)bh * NC + c) * 64 + i] = cum;
    const size_t eb = ((size_t)bh * NC + c) * 4096 + (size_t)i * 64 + jq * 16;
#pragma unroll
    for (int q = 0; q < 4; ++q)
        *(float4*)&E[eb + q * 4] = make_float4(st[q * 4 + 0], st[q * 4 + 1],
                                               st[q * 4 + 2], st[q * 4 + 3]);
}

// pass2: boundary states. grid = B*H, 256 thr.
__global__ __launch_bounds__(256)
void wkv7_pass2(const float* __restrict__ E, const float* __restrict__ Dend,
                float* __restrict__ S0, int Bn, int Tn, int Hn)
{
    const int bh = blockIdx.x;
    const int tid = threadIdx.x;
    const int i  = tid >> 2;
    const int jq = tid & 3;
    const size_t base = (size_t)bh * NC * 4096 + (size_t)i * 64 + jq * 16;

    float S[16];
#pragma unroll
    for (int q = 0; q < 16; ++q) S[q] = 0.f;

    for (int c = 0; c < NC; ++c) {
        const size_t idx = base + (size_t)c * 4096;
#pragma unroll
        for (int q = 0; q < 4; ++q)
            *(float4*)&S0[idx + q * 4] = make_float4(S[q * 4 + 0], S[q * 4 + 1],
                                                     S[q * 4 + 2], S[q * 4 + 3]);
        if (c + 1 < NC) {
            const float D = Dend[((size_t)bh * NC + c) * 64 + i];
#pragma unroll
            for (int q = 0; q < 4; ++q) {
                const float4 e = *(const float4*)&E[idx + q * 4];
                S[q * 4 + 0] = D * S[q * 4 + 0] + e.x;
                S[q * 4 + 1] = D * S[q * 4 + 1] + e.y;
                S[q * 4 + 2] = D * S[q * 4 + 2] + e.z;
                S[q * 4 + 3] = D * S[q * 4 + 3] + e.w;
            }
        }
    }
}

// pass3: ycorr[t,i] = (prod_{s<=t} w_s[i]) * sum_j S0[i,j] r_t[j].
__global__ __launch_bounds__(256)
void wkv7_pass3(const u16* __restrict__ r, const float* __restrict__ w,
                const float* __restrict__ S0, float* __restrict__ ycorr,
                int Bn, int Tn, int Hn)
{
    const int blk = blockIdx.x;
    const int c  = blk & (NC - 1);
    const int bh = blk >> 4;
    const int h  = bh % Hn, b = bh / Hn;
    const int tid = threadIdx.x;
    const int i  = tid >> 2;
    const int jq = tid & 3;
    const int C  = Hn * 64;

    const size_t sb = ((size_t)bh * NC + c) * 4096 + (size_t)i * 64 + jq * 16;
    float4 s0[4];
#pragma unroll
    for (int q = 0; q < 4; ++q) s0[q] = *(const float4*)&S0[sb + q * 4];

    size_t off = ((size_t)b * Tn + c * CL) * C + h * 64;
    float cum = 1.f;
    for (int t = 0; t < CL; ++t) {
        cum *= w[off + i];
        float p = 0.f;
#pragma unroll
        for (int q = 0; q < 4; ++q) {
            const float4 r4 = b2f4(*(const ushort4*)&r[off + jq * 16 + q * 4]);
            p += s0[q].x * r4.x + s0[q].y * r4.y + s0[q].z * r4.z + s0[q].w * r4.w;
        }
        p += __shfl_xor(p, 1);
        p += __shfl_xor(p, 2);
        if (jq == 0) ycorr[off + i] = cum * p;
        off += C;
    }
}

// ---- fused LN + rkv + gate (y = y0 + ycorr), r/k/v/g bf16, bf16 out ----
__global__ __launch_bounds__(256)
void ln_rkv_gate2(const float* __restrict__ y0, const float* __restrict__ yc,
                  const u16* __restrict__ r, const u16* __restrict__ k,
                  const u16* __restrict__ v, const u16* __restrict__ g,
                  const float* __restrict__ r_k, const float* __restrict__ lng,
                  const float* __restrict__ lnb, u16* __restrict__ z, int C)
{
    const int m   = blockIdx.x;
    const int tid = threadIdx.x;
    const size_t base = (size_t)m * C;
    const int c = tid << 2;

    const float4 a  = *(const float4*)&y0[base + c];
    const float4 b4 = *(const float4*)&yc[base + c];
    float4 y4;
    y4.x = a.x + b4.x; y4.y = a.y + b4.y; y4.z = a.z + b4.z; y4.w = a.w + b4.w;

    float s  = y4.x + y4.y + y4.z + y4.w;
    float ss = y4.x * y4.x + y4.y * y4.y + y4.z * y4.z + y4.w * y4.w;
#pragma unroll
    for (int o = 1; o < 64; o <<= 1) { s += __shfl_xor(s, o); ss += __shfl_xor(ss, o); }
    __shared__ float red[2][4];
    const int wid = tid >> 6, lid = tid & 63;
    if (lid == 0) { red[0][wid] = s; red[1][wid] = ss; }
    __syncthreads();
    s  = red[0][0] + red[0][1] + red[0][2] + red[0][3];
    ss = red[1][0] + red[1][1] + red[1][2] + red[1][3];
    const float mean = s / (float)C;
    const float var  = ss / (float)C - mean * mean;
    const float inv  = rsqrtf(var + 1e-5f);

    const float4 r4  = b2f4(*(const ushort4*)&r[base + c]);
    const float4 k4  = b2f4(*(const ushort4*)&k[base + c]);
    const float4 rk4 = *(const float4*)&r_k[c];
    float p = r4.x * k4.x * rk4.x + r4.y * k4.y * rk4.y + r4.z * k4.z * rk4.z + r4.w * k4.w * rk4.w;
    p += __shfl_xor(p, 1); p += __shfl_xor(p, 2); p += __shfl_xor(p, 4); p += __shfl_xor(p, 8);

    const float4 v4 = b2f4(*(const ushort4*)&v[base + c]);
    const float4 g4 = b2f4(*(const ushort4*)&g[base + c]);
    const float4 lg = *(const float4*)&lng[c];
    const float4 lb = *(const float4*)&lnb[c];
    ushort4 res;
    res.x = f2b(((y4.x - mean) * inv * lg.x + lb.x + p * v4.x) * g4.x);
    res.y = f2b(((y4.y - mean) * inv * lg.y + lb.y + p * v4.y) * g4.y);
    res.z = f2b(((y4.z - mean) * inv * lg.z + lb.z + p * v4.z) * g4.z);
    res.w = f2b(((y4.w - mean) * inv * lg.w + lb.w + p * v4.w) * g4.w);
    *(ushort4*)&z[base + c] = res;
}

// ============================ FALLBACK (round-1 fp32) =======================

#define BM 64
#define BN 64
#define BK 32
enum { A_PLAIN = 0, A_MIX = 1 };
enum { EP_STORE = 0, EP_TANH = 1, EP_W = 2, EP_SIGMOID = 3, EP_AK = 4, EP_VBLEND = 5 };

template<int AMODE, int EPI>
__global__ __launch_bounds__(256)
void gemm_nt(const float* __restrict__ A, const float* __restrict__ tm,
             const float* __restrict__ W, float* __restrict__ O,
             const float* __restrict__ bias, const float* __restrict__ extra,
             int M, int K, int N, int Tdim)
{
    __shared__ float As[BK][BM + 4];
    __shared__ float Bs[BK][BN + 4];
    const int tid  = threadIdx.x;
    const int m0   = blockIdx.y * BM;
    const int n0   = blockIdx.x * BN;
    const int lrow = tid >> 3;
    const int lcol = (tid & 7) << 2;
    const int ty   = tid >> 4;
    const int tx   = tid & 15;
    float acc[4][4] = {{0.f}};

    for (int k0 = 0; k0 < K; k0 += BK) {
#pragma unroll
        for (int rr = 0; rr < 2; ++rr) {
            const int row = lrow + rr * 32;
            const int m   = m0 + row;
            float4 av;
            if (AMODE == A_MIX) {
                const float4 xc = *(const float4*)&A[(size_t)m * K + k0 + lcol];
                float4 xp = make_float4(0.f, 0.f, 0.f, 0.f);
                if ((m % Tdim) != 0)
                    xp = *(const float4*)&A[(size_t)(m - 1) * K + k0 + lcol];
                const float4 tc = *(const float4*)&tm[k0 + lcol];
                av.x = xc.x + (xp.x - xc.x) * tc.x;
                av.y = xc.y + (xp.y - xc.y) * tc.y;
                av.z = xc.z + (xp.z - xc.z) * tc.z;
                av.w = xc.w + (xp.w - xc.w) * tc.w;
            } else {
                av = *(const float4*)&A[(size_t)m * K + k0 + lcol];
            }
            As[lcol + 0][row] = av.x; As[lcol + 1][row] = av.y;
            As[lcol + 2][row] = av.z; As[lcol + 3][row] = av.w;
            const float4 bv = *(const float4*)&W[(size_t)(n0 + row) * K + k0 + lcol];
            Bs[lcol + 0][row] = bv.x; Bs[lcol + 1][row] = bv.y;
            Bs[lcol + 2][row] = bv.z; Bs[lcol + 3][row] = bv.w;
        }
        __syncthreads();
#pragma unroll
        for (int kk = 0; kk < BK; ++kk) {
            const float4 a4 = *(const float4*)&As[kk][ty << 2];
            const float4 b4 = *(const float4*)&Bs[kk][tx << 2];
            acc[0][0] += a4.x * b4.x; acc[0][1] += a4.x * b4.y; acc[0][2] += a4.x * b4.z; acc[0][3] += a4.x * b4.w;
            acc[1][0] += a4.y * b4.x; acc[1][1] += a4.y * b4.y; acc[1][2] += a4.y * b4.z; acc[1][3] += a4.y * b4.w;
            acc[2][0] += a4.z * b4.x; acc[2][1] += a4.z * b4.y; acc[2][2] += a4.z * b4.z; acc[2][3] += a4.z * b4.w;
            acc[3][0] += a4.w * b4.x; acc[3][1] += a4.w * b4.y; acc[3][2] += a4.w * b4.z; acc[3][3] += a4.w * b4.w;
        }
        __syncthreads();
    }

#pragma unroll
    for (int ii = 0; ii < 4; ++ii) {
        const int m = m0 + (ty << 2) + ii;
        const int n = n0 + (tx << 2);
        const size_t o = (size_t)m * N + n;
        const float a0v = acc[ii][0], a1v = acc[ii][1], a2v = acc[ii][2], a3v = acc[ii][3];
        float4 res;
        if (EPI == EP_STORE) {
            res = make_float4(a0v, a1v, a2v, a3v);
        } else if (EPI == EP_TANH) {
            res = make_float4(tanhf(a0v), tanhf(a1v), tanhf(a2v), tanhf(a3v));
        } else if (EPI == EP_SIGMOID) {
            res = make_float4(sigf(a0v), sigf(a1v), sigf(a2v), sigf(a3v));
        } else if (EPI == EP_W) {
            const float4 b = *(const float4*)&bias[n];
            res.x = expf(-0.606531f * sigf(b.x + a0v));
            res.y = expf(-0.606531f * sigf(b.y + a1v));
            res.z = expf(-0.606531f * sigf(b.z + a2v));
            res.w = expf(-0.606531f * sigf(b.w + a3v));
        } else if (EPI == EP_AK) {
            const float4 b  = *(const float4*)&bias[n];
            const float4 ka = *(const float4*)&extra[n];
            const float4 kv = *(const float4*)&O[o];
            res.x = kv.x * (1.f + (sigf(b.x + a0v) - 1.f) * ka.x);
            res.y = kv.y * (1.f + (sigf(b.y + a1v) - 1.f) * ka.y);
            res.z = kv.z * (1.f + (sigf(b.z + a2v) - 1.f) * ka.z);
            res.w = kv.w * (1.f + (sigf(b.w + a3v) - 1.f) * ka.w);
        } else {
            const float4 b  = *(const float4*)&bias[n];
            const float4 vf = *(const float4*)&extra[o];
            const float4 vv = *(const float4*)&O[o];
            float sx;
            sx = sigf(b.x + a0v); res.x = vv.x + (vf.x - vv.x) * sx;
            sx = sigf(b.y + a1v); res.y = vv.y + (vf.y - vv.y) * sx;
            sx = sigf(b.z + a2v); res.z = vv.z + (vf.z - vv.z) * sx;
            sx = sigf(b.w + a3v); res.w = vv.w + (vf.w - vv.w) * sx;
        }
        *(float4*)&O[o] = res;
    }
}

__global__ __launch_bounds__(64)
void wkv7_scan(const float* __restrict__ r, const float* __restrict__ w,
               const float* __restrict__ k, const float* __restrict__ v,
               float* __restrict__ y, int Bn, int Tn, int Hn)
{
    const int blk  = blockIdx.x;
    const int s    = blk & 3;
    const int h    = (blk >> 2) % Hn;
    const int b    = blk / (4 * Hn);
    const int lane = threadIdx.x;
    const int il   = lane >> 2;
    const int q    = lane & 3;
    const int i    = s * 16 + il;
    const int C    = Hn * 64;
    const size_t base = (size_t)b * Tn * C + h * 64;

    float st[16];
#pragma unroll
    for (int j = 0; j < 16; ++j) st[j] = 0.f;

    __shared__ float vs[4][64];
    __shared__ float rs[4][64];

    for (int t0 = 0; t0 < Tn; t0 += 4) {
        float vl[4], rl[4], wl[4], kl[4];
#pragma unroll
        for (int u = 0; u < 4; ++u) {
            const size_t off = base + (size_t)(t0 + u) * C;
            vl[u] = v[off + lane]; rl[u] = r[off + lane];
            wl[u] = w[off + i];    kl[u] = k[off + i];
        }
        __syncthreads();
#pragma unroll
        for (int u = 0; u < 4; ++u) { vs[u][lane] = vl[u]; rs[u][lane] = rl[u]; }
        __syncthreads();
#pragma unroll
        for (int u = 0; u < 4; ++u) {
            const float wi = wl[u], ki = kl[u];
            float yi = 0.f;
#pragma unroll
            for (int jg = 0; jg < 4; ++jg) {
                const float4 v4 = *(const float4*)&vs[u][q * 16 + jg * 4];
                const float4 r4 = *(const float4*)&rs[u][q * 16 + jg * 4];
                const int j = jg * 4;
                st[j + 0] = st[j + 0] * wi + ki * v4.x; yi += st[j + 0] * r4.x;
                st[j + 1] = st[j + 1] * wi + ki * v4.y; yi += st[j + 1] * r4.y;
                st[j + 2] = st[j + 2] * wi + ki * v4.z; yi += st[j + 2] * r4.z;
                st[j + 3] = st[j + 3] * wi + ki * v4.w; yi += st[j + 3] * r4.w;
            }
            yi += __shfl_xor(yi, 1);
            yi += __shfl_xor(yi, 2);
            if (q == 0) y[base + (size_t)(t0 + u) * C + i] = yi;
        }
    }
}

__global__ __launch_bounds__(256)
void ln_rkv_gate(const float* __restrict__ y, const float* __restrict__ r,
                 const float* __restrict__ k, const float* __restrict__ v,
                 const float* __restrict__ g, const float* __restrict__ r_k,
                 const float* __restrict__ lng, const float* __restrict__ lnb,
                 float* __restrict__ z, int C)
{
    const int m   = blockIdx.x;
    const int tid = threadIdx.x;
    const size_t base = (size_t)m * C;
    const int c = tid << 2;

    const float4 y4 = *(const float4*)&y[base + c];
    float s  = y4.x + y4.y + y4.z + y4.w;
    float ss = y4.x * y4.x + y4.y * y4.y + y4.z * y4.z + y4.w * y4.w;
#pragma unroll
    for (int o = 1; o < 64; o <<= 1) { s += __shfl_xor(s, o); ss += __shfl_xor(ss, o); }
    __shared__ float red[2][4];
    const int wid = tid >> 6, lid = tid & 63;
    if (lid == 0) { red[0][wid] = s; red[1][wid] = ss; }
    __syncthreads();
    s  = red[0][0] + red[0][1] + red[0][2] + red[0][3];
    ss = red[1][0] + red[1][1] + red[1][2] + red[1][3];
    const float mean = s / (float)C;
    const float var  = ss / (float)C - mean * mean;
    const float inv  = rsqrtf(var + 1e-5f);

    const float4 r4  = *(const float4*)&r[base + c];
    const float4 k4  = *(const float4*)&k[base + c];
    const float4 rk4 = *(const float4*)&r_k[c];
    float p = r4.x * k4.x * rk4.x + r4.y * k4.y * rk4.y + r4.z * k4.z * rk4.z + r4.w * k4.w * rk4.w;
    p += __shfl_xor(p, 1); p += __shfl_xor(p, 2); p += __shfl_xor(p, 4); p += __shfl_xor(p, 8);

    const float4 v4 = *(const float4*)&v[base + c];
    const float4 g4 = *(const float4*)&g[base + c];
    const float4 lg = *(const float4*)&lng[c];
    const float4 lb = *(const float4*)&lnb[c];
    float4 res;
    res.x = ((y4.x - mean) * inv * lg.x + lb.x + p * v4.x) * g4.x;
    res.y = ((y4.y - mean) * inv * lg.y + lb.y + p * v4.y) * g4.y;
    res.z = ((y4.z - mean) * inv * lg.z + lb.z + p * v4.z) * g4.z;
    res.w = ((y4.w - mean) * inv * lg.w + lb.w + p * v4.w) * g4.w;
    *(float4*)&z[base + c] = res;
}

// ============================ LAUNCH ========================================

extern "C" void kernel_launch(void* const* d_in, const int* in_sizes, int n_in,
                              void* d_out, int out_size, void* d_ws, size_t ws_size,
                              hipStream_t stream)
{
    const float* x    = (const float*)d_in[0];
    const float* vfst = (const float*)d_in[1];
    const float* Wr   = (const float*)d_in[2];
    const float* Wk   = (const float*)d_in[3];
    const float* Wv   = (const float*)d_in[4];
    const float* Wo   = (const float*)d_in[5];
    const float* Wg1  = (const float*)d_in[6];
    const float* Wg2  = (const float*)d_in[7];
    const float* W1   = (const float*)d_in[8];
    const float* W2   = (const float*)d_in[9];
    const float* A1   = (const float*)d_in[10];
    const float* A2   = (const float*)d_in[11];
    const float* V1   = (const float*)d_in[12];
    const float* V2   = (const float*)d_in[13];
    const float* tm_r = (const float*)d_in[14];
    const float* tm_w = (const float*)d_in[15];
    const float* tm_k = (const float*)d_in[16];
    const float* tm_v = (const float*)d_in[17];
    const float* tm_a = (const float*)d_in[18];
    const float* tm_g = (const float*)d_in[19];
    const float* w0   = (const float*)d_in[20];
    const float* a0   = (const float*)d_in[21];
    const float* v0   = (const float*)d_in[22];
    const float* k_a  = (const float*)d_in[24];
    const float* r_k  = (const float*)d_in[25];
    const float* ln_g = (const float*)d_in[26];
    const float* ln_b = (const float*)d_in[27];
    float* out = (float*)d_out;

    const int Bn = 2, Tn = 2048, C = 1024, Hh = 16;
    const int M = Bn * Tn, K = C, N = C;
    const size_t MBy = (size_t)1 << 20;
    const size_t NEED = 172 * MBy;

    if (ws_size >= NEED) {
        unsigned char* w8 = (unsigned char*)d_ws;
        u16* wb    = (u16*)(w8 + 0);            // 10 x 2MB bf16 weights
        u16* w1cat = (u16*)(w8 + 20 * MBy);     // 4MB [hi|hi]
        u16* w2cat = (u16*)(w8 + 24 * MBy);     // 4MB [hi|hi]
        u16* axr   = (u16*)(w8 + 28 * MBy);     // 8MB each
        u16* axk   = (u16*)(w8 + 36 * MBy);
        u16* axv   = (u16*)(w8 + 44 * MBy);
        u16* axa   = (u16*)(w8 + 52 * MBy);
        u16* axg   = (u16*)(w8 + 60 * MBy);
        u16* axw   = (u16*)(w8 + 68 * MBy);     // 16MB [hi|lo]
        u16* btw   = (u16*)(w8 + 84 * MBy);     // 16MB [hi|lo]
        u16* bt1a  = (u16*)(w8 + 100 * MBy);    // 8MB each
        u16* bt1g  = (u16*)(w8 + 108 * MBy);
        u16* bt1v  = (u16*)(w8 + 116 * MBy);
        u16* br    = (u16*)(w8 + 124 * MBy);    // bf16 r/k/v/g, 8MB each
        u16* bk    = (u16*)(w8 + 132 * MBy);
        u16* bv    = (u16*)(w8 + 140 * MBy);
        float* bw  = (float*)(w8 + 148 * MBy);  // fp32 decay, 16MB
        u16* bg    = (u16*)(w8 + 164 * MBy);
        // scan-phase aliases (ax*/btw dead after GEMM stage 2)
        float* by   = (float*)(w8 + 28 * MBy);  // y zero-start, 16MB
        float* byc  = (float*)(w8 + 44 * MBy);  // ycorr, 16MB
        float* bE   = (float*)(w8 + 60 * MBy);  // end states, 8MB
        float* bDd  = (float*)(w8 + 68 * MBy);  // chunk-end decay, 128KB
        float* bS0  = (float*)(w8 + 70 * MBy);  // boundary states, 8MB
        u16*  bz    = (u16*)(w8 + 84 * MBy);    // LN output, 8MB

        u16* wWr  = wb;              u16* wWk  = wb + (1u << 20);
        u16* wWv  = wb + (2u << 20); u16* wWo  = wb + (3u << 20);
        u16* wWg1 = wb + (4u << 20); u16* wWg2 = wb + (5u << 20);
        u16* wA1  = wb + (6u << 20); u16* wA2  = wb + (7u << 20);
        u16* wV1  = wb + (8u << 20); u16* wV2  = wb + (9u << 20);

        P10 p10;
        p10.p[0] = Wr;  p10.p[1] = Wk;  p10.p[2] = Wv;  p10.p[3] = Wo;
        p10.p[4] = Wg1; p10.p[5] = Wg2; p10.p[6] = A1;  p10.p[7] = A2;
        p10.p[8] = V1;  p10.p[9] = V2;

        conv_w10<<<dim3(10240), dim3(256), 0, stream>>>(p10, wb);
        conv_cat2<<<dim3(1024), dim3(256), 0, stream>>>(W1, W2, w1cat, w2cat);
        prep_act<<<dim3(4096), dim3(256), 0, stream>>>(x, tm_r, tm_w, tm_k, tm_v, tm_a, tm_g,
                                                       axr, axk, axv, axa, axg, axw, Tn);

        // stage 1: 7 independent GEMMs
        GemmBatch s1;
        s1.j[0] = { axw, w1cat, nullptr, btw,  nullptr, nullptr, 2048, FE_TANHCAT };
        s1.j[1] = { axr, wWr,   nullptr, br,   nullptr, nullptr, 1024, FE_B16 };
        s1.j[2] = { axk, wWk,   nullptr, bk,   nullptr, nullptr, 1024, FE_B16 };
        s1.j[3] = { axv, wWv,   nullptr, bv,   nullptr, nullptr, 1024, FE_B16 };
        s1.j[4] = { axa, wA1,   nullptr, bt1a, nullptr, nullptr, 1024, FE_B16 };
        s1.j[5] = { axg, wWg1,  nullptr, bt1g, nullptr, nullptr, 1024, FE_SIGB };
        s1.j[6] = { axv, wV1,   nullptr, bt1v, nullptr, nullptr, 1024, FE_B16 };
        mfma_batch<<<dim3(7 * 256), dim3(256), 0, stream>>>(s1);

        // stage 2: 4 dependent GEMMs
        GemmBatch s2;
        s2.j[0] = { btw,  w2cat, bw,      nullptr, w0, nullptr, 2048, FE_W };
        s2.j[1] = { bt1a, wA2,   nullptr, bk,   a0, k_a,     1024, FE_AK };
        s2.j[2] = { bt1g, wWg2,  nullptr, bg,   nullptr, nullptr, 1024, FE_B16 };
        s2.j[3] = { bt1v, wV2,   nullptr, bv,   v0, vfst,    1024, FE_VBLEND };
        s2.j[4] = s2.j[0]; s2.j[5] = s2.j[0]; s2.j[6] = s2.j[0];
        mfma_batch<<<dim3(4 * 256), dim3(256), 0, stream>>>(s2);

        // chunked scan
        wkv7_pass1<<<dim3(Bn * Hh * NC * 4), dim3(64), 0, stream>>>(br, bw, bk, bv,
                                                                    by, bDd, bE, Bn, Tn, Hh);
        wkv7_pass2<<<dim3(Bn * Hh), dim3(256), 0, stream>>>(bE, bDd, bS0, Bn, Tn, Hh);
        wkv7_pass3<<<dim3(Bn * Hh * NC), dim3(256), 0, stream>>>(br, bw, bS0, byc, Bn, Tn, Hh);

        // LN + rkv + gate -> bz (bf16)
        ln_rkv_gate2<<<dim3(M), dim3(256), 0, stream>>>(by, byc, br, bk, bv, bg,
                                                        r_k, ln_g, ln_b, bz, C);
        // out = z @ Wo^T
        GemmBatch s3;
        s3.j[0] = { bz, wWo, out, nullptr, nullptr, nullptr, 1024, FE_F32 };
        s3.j[1] = s3.j[0]; s3.j[2] = s3.j[0]; s3.j[3] = s3.j[0];
        s3.j[4] = s3.j[0]; s3.j[5] = s3.j[0]; s3.j[6] = s3.j[0];
        mfma_batch<<<dim3(256), dim3(256), 0, stream>>>(s3);
        return;
    }

    // -------- fallback: round-1 fp32 path (96MB ws) --------
    const size_t S = (size_t)M * C;
    float* ws = (float*)d_ws;
    float* fr = ws;
    float* fk = ws + S;
    float* fv = ws + 2 * S;
    float* fw = ws + 3 * S;
    float* fg = ws + 4 * S;
    float* ft = ws + 5 * S;
    float* fy = ft;

    dim3 grid(N / BN, M / BM);
    dim3 blk(256);

    gemm_nt<A_MIX, EP_STORE><<<grid, blk, 0, stream>>>(x, tm_r, Wr, fr, nullptr, nullptr, M, K, N, Tn);
    gemm_nt<A_MIX, EP_STORE><<<grid, blk, 0, stream>>>(x, tm_k, Wk, fk, nullptr, nullptr, M, K, N, Tn);
    gemm_nt<A_MIX, EP_STORE><<<grid, blk, 0, stream>>>(x, tm_v, Wv, fv, nullptr, nullptr, M, K, N, Tn);
    gemm_nt<A_MIX, EP_TANH><<<grid, blk, 0, stream>>>(x, tm_w, W1, ft, nullptr, nullptr, M, K, N, Tn);
    gemm_nt<A_PLAIN, EP_W><<<grid, blk, 0, stream>>>(ft, nullptr, W2, fw, w0, nullptr, M, K, N, Tn);
    gemm_nt<A_MIX, EP_STORE><<<grid, blk, 0, stream>>>(x, tm_a, A1, ft, nullptr, nullptr, M, K, N, Tn);
    gemm_nt<A_PLAIN, EP_AK><<<grid, blk, 0, stream>>>(ft, nullptr, A2, fk, a0, k_a, M, K, N, Tn);
    gemm_nt<A_MIX, EP_SIGMOID><<<grid, blk, 0, stream>>>(x, tm_g, Wg1, ft, nullptr, nullptr, M, K, N, Tn);
    gemm_nt<A_PLAIN, EP_STORE><<<grid, blk, 0, stream>>>(ft, nullptr, Wg2, fg, nullptr, nullptr, M, K, N, Tn);
    gemm_nt<A_MIX, EP_STORE><<<grid, blk, 0, stream>>>(x, tm_v, V1, ft, nullptr, nullptr, M, K, N, Tn);
    gemm_nt<A_PLAIN, EP_VBLEND><<<grid, blk, 0, stream>>>(ft, nullptr, V2, fv, v0, vfst, M, K, N, Tn);
    wkv7_scan<<<dim3(Bn * Hh * 4), dim3(64), 0, stream>>>(fr, fw, fk, fv, fy, Bn, Tn, Hh);
    ln_rkv_gate<<<dim3(M), dim3(256), 0, stream>>>(fy, fr, fk, fv, fg, r_k, ln_g, ln_b, fy, C);
    gemm_nt<A_PLAIN, EP_STORE><<<grid, blk, 0, stream>>>(fy, nullptr, Wo, out, nullptr, nullptr, M, K, N, Tn);
}